// Round 8
// baseline (950.116 us; speedup 1.0000x reference)
//
#include <hip/hip_runtime.h>
#include <math.h>
#include <stdio.h>
#include <stdint.h>

#define N_SRC 200000
#define N_DST 100000
#define NE    400000
// IN=128, H=8, D=32, H*D=256

#define SCAN_CHUNK 1024
#define NSCAN ((N_DST + SCAN_CHUNK - 1) / SCAN_CHUNK)   // 98

typedef short bf16x8 __attribute__((ext_vector_type(8)));
typedef float f32x4 __attribute__((ext_vector_type(4)));

__device__ __forceinline__ float bflo(unsigned int u) { return __uint_as_float(u << 16); }
__device__ __forceinline__ float bfhi(unsigned int u) { return __uint_as_float(u & 0xFFFF0000u); }
__device__ __forceinline__ unsigned short f2bf(float f) {
    unsigned int u = __float_as_uint(f);
    u += 0x7FFFu + ((u >> 16) & 1u);       // round-to-nearest-even
    return (unsigned short)(u >> 16);
}
// pack two f32 -> (bf16(f1)<<16)|bf16(f0) by truncation: single v_perm_b32
__device__ __forceinline__ unsigned int packbf(float f0, float f1) {
    return __builtin_amdgcn_perm(__float_as_uint(f1), __float_as_uint(f0), 0x07060302u);
}

// ---------------------------------------------------------------------------
// Staged MFMA GEMM with DEEP-BATCH register staging (T14 issue-early/write-late).
// out[n][c] = sum_k A[n][k]*W[c][k] (+bias+add_c+add_n).
// The fix vs r7: staging issues BATCH (8-14) independent uint4 loads per thread
// with ZERO dependent ops between them, then drains in a separate loop. First
// LDS write waits vmcnt(BATCH-1); remaining loads (~160-220 cache lines/wave)
// stay in flight -> Little's law gives ~5+ TB/s vs the measured 1.14 ceiling
// caused by depth-4 load->consume chains in r3-r7.
// K padding: pad cols zeroed at drain; OOB tile rows clamped (their MFMA
// products land only in D rows >= N which are never stored).
// A: f32 [N][K] (ABF=false) or bf16 [N][K] (ABF=true).
// ---------------------------------------------------------------------------
template<bool ABF, int K, int KP, int HALVES, int NT, int BATCH>
__global__ __launch_bounds__(256) void gemm_batch(
    const void* __restrict__ Ap, const unsigned short* __restrict__ Wf,
    const float* __restrict__ bias, const float* __restrict__ add_n,
    const float* __restrict__ add_c,
    unsigned short* __restrict__ out_lin, unsigned short* __restrict__ out_exp,
    int N, int C)
{
    constexpr int KST   = KP / 32;            // total k-steps
    constexpr int KSH   = KST / HALVES;       // k-steps per half
    constexpr int HALFW = KP / HALVES;        // elements per half
    constexpr int ELB   = ABF ? 2 : 4;        // bytes/element in global A
    constexpr int ROWB  = HALFW * ELB;        // global bytes per row-half
    constexpr int LOADS = (128 * ROWB) / (256 * 16);  // uint4 loads per thread
    constexpr int NB    = LOADS / BATCH;
    static_assert(LOADS % BATCH == 0, "batch divisibility");
    constexpr int SRB   = (HALFW + 8) * 2;    // LDS row stride bytes
    __shared__ __align__(16) char As[128 * SRB];

    const int tid  = threadIdx.x;
    const int lane = tid & 63;
    const int wv   = tid >> 6;
    const int fr   = lane & 15;
    const int fq   = lane >> 4;
    const int row0 = blockIdx.y * 128;
    const int nb0  = blockIdx.x * NT;

    const float* Af = (const float*)Ap;
    const unsigned short* Ab = (const unsigned short*)Ap;

    f32x4 acc[2][NT];
#pragma unroll
    for (int m = 0; m < 2; ++m)
#pragma unroll
        for (int n = 0; n < NT; ++n) acc[m][n] = (f32x4){0.f, 0.f, 0.f, 0.f};

    for (int h = 0; h < HALVES; ++h) {
        if (h) __syncthreads();     // protect LDS reuse across halves
#pragma unroll
        for (int b = 0; b < NB; ++b) {
            uint4 buf[BATCH];
            int   loff[BATCH];      // LDS dest byte offset
            int   kel[BATCH];       // first k element of this load (f32 path)
            // ---- issue: BATCH independent coalesced loads, no dependent ops ----
#pragma unroll
            for (int i = 0; i < BATCH; ++i) {
                int fo   = ((b * BATCH + i) * 256 + tid) * 16;  // byte off in slab
                int row  = fo / ROWB;                            // const-div
                int colb = fo - row * ROWB;
                int rr   = row0 + row; if (rr >= N) rr = N - 1;
                if (ABF) {
                    loff[i] = row * SRB + colb;
                    buf[i]  = *(const uint4*)((const char*)Ab + (long)rr * (K * 2) + h * ROWB + colb);
                } else {
                    int k0  = h * HALFW + (colb >> 2);
                    kel[i]  = k0;
                    loff[i] = row * SRB + (colb >> 1);
                    long gb = (long)rr * (K * 4) + (k0 < K ? (long)h * ROWB + colb : 0);
                    buf[i]  = *(const uint4*)((const char*)Af + gb);
                }
            }
            // ---- drain: pack + LDS write (vmcnt counts down through batch) ----
#pragma unroll
            for (int i = 0; i < BATCH; ++i) {
                if (ABF) {
                    *(uint4*)(As + loff[i]) = buf[i];
                } else {
                    uint2 w;
                    w.x = packbf(__uint_as_float(buf[i].x), __uint_as_float(buf[i].y));
                    w.y = packbf(__uint_as_float(buf[i].z), __uint_as_float(buf[i].w));
                    if (K < KP && kel[i] >= K) { w.x = 0u; w.y = 0u; }
                    *(uint2*)(As + loff[i]) = w;
                }
            }
        }
        __syncthreads();
        // ---- MFMA sweep over this half (no barriers inside) ----
#pragma unroll 2
        for (int ksl = 0; ksl < KSH; ++ksl) {
            const int ks = h * KSH + ksl;
            uint4 pb[NT];
#pragma unroll
            for (int n = 0; n < NT; ++n)
                pb[n] = *(const uint4*)&Wf[(size_t)(((nb0 + n) * KST + ks) * 64 + lane) * 8];
            bf16x8 a0 = *(const bf16x8*)(As + (wv * 32 +      fr) * SRB + ksl * 64 + fq * 16);
            bf16x8 a1 = *(const bf16x8*)(As + (wv * 32 + 16 + fr) * SRB + ksl * 64 + fq * 16);
#pragma unroll
            for (int n = 0; n < NT; ++n) {
                acc[0][n] = __builtin_amdgcn_mfma_f32_16x16x32_bf16(a0, *(bf16x8*)&pb[n], acc[0][n], 0, 0, 0);
                acc[1][n] = __builtin_amdgcn_mfma_f32_16x16x32_bf16(a1, *(bf16x8*)&pb[n], acc[1][n], 0, 0, 0);
            }
        }
    }

    // epilogue: D col = lane&15, row = (lane>>4)*4 + reg (measured m89/m91)
    float bc[NT];
#pragma unroll
    for (int n = 0; n < NT; ++n) {
        int col = (nb0 + n) * 16 + fr;
        float b = 0.f;
        if (bias)  b += bias[col];
        if (add_c) b += add_c[col];
        bc[n] = b;
    }
#pragma unroll
    for (int m = 0; m < 2; ++m) {
#pragma unroll
        for (int j = 0; j < 4; ++j) {
            int row = row0 + wv * 32 + m * 16 + fq * 4 + j;
            if (row >= N) continue;
#pragma unroll
            for (int n = 0; n < NT; ++n) {
                int col = (nb0 + n) * 16 + fr;
                float v = acc[m][n][j] + bc[n];
                if (add_n) v += add_n[(long)row * C + col];
                long o = (long)row * C + col;
                if (out_lin) out_lin[o] = f2bf(v);
                if (out_exp) out_exp[o] = f2bf(expf(v));
            }
        }
    }
}

// ---------------------------------------------------------------------------
// Weight f32 [C][K] -> bf16 B-fragment layout, zero-padded to Kp (KS=Kp/32):
// dst[((n*KS+ks)*64+l)*8 + j] = W[n*16 + (l&15)][ks*32 + (l>>4)*8 + j]
// ---------------------------------------------------------------------------
__global__ void wconv_frag(const float* __restrict__ src, unsigned short* __restrict__ dst,
                           int C, int K, int Kp)
{
    int KS = Kp >> 5;
    int total = C * Kp;
    for (int i = blockIdx.x * blockDim.x + threadIdx.x; i < total; i += gridDim.x * blockDim.x) {
        int j  = i & 7;
        int l  = (i >> 3) & 63;
        int t  = i >> 9;
        int ks = t % KS;
        int n  = t / KS;
        int col = n * 16 + (l & 15);
        int k   = ks * 32 + ((l >> 4) << 3) + j;
        dst[i] = (k < K) ? f2bf(src[(long)col * K + k]) : (unsigned short)0;
    }
}

// ---------------------------------------------------------------------------
// Setup: fold W_na into Q/K (wq_eff/wk_eff [8][128]), fold W_merge x W_eattn
// into Wcomb [8][128], cm[8] = b_merge + W_merge[:,8:] . b_eattn
// ---------------------------------------------------------------------------
__global__ void eff_setup(const float* __restrict__ Wq, const float* __restrict__ bq,
                          const float* __restrict__ na_item,
                          const float* __restrict__ Wk, const float* __restrict__ bk,
                          const float* __restrict__ na_user,
                          const float* __restrict__ W_merge, const float* __restrict__ b_merge,
                          const float* __restrict__ W_eattn, const float* __restrict__ b_eattn,
                          float* __restrict__ wq_eff, float* __restrict__ bq_eff,
                          float* __restrict__ wk_eff, float* __restrict__ bk_eff,
                          float* __restrict__ Wcomb, float* __restrict__ cmv)
{
    int tid = threadIdx.x;
    for (int idx = tid; idx < 1024; idx += 256) {
        int h = idx >> 7, k = idx & 127;
        float s1 = 0.f, s2 = 0.f, s3 = 0.f;
        for (int d = 0; d < 32; ++d) {
            s1 += Wq[(h * 32 + d) * 128 + k] * na_item[d];
            s2 += Wk[(h * 32 + d) * 128 + k] * na_user[d];
        }
        for (int j = 0; j < 8; ++j)
            s3 += W_merge[h * 16 + 8 + j] * W_eattn[j * 128 + k];
        wq_eff[idx] = s1;
        wk_eff[idx] = s2;
        Wcomb[idx]  = s3;
    }
    if (tid < 8) {
        float s1 = 0.f, s2 = 0.f, s3 = b_merge[tid];
        for (int d = 0; d < 32; ++d) {
            s1 += bq[tid * 32 + d] * na_item[d];
            s2 += bk[tid * 32 + d] * na_user[d];
        }
        for (int j = 0; j < 8; ++j) s3 += W_merge[tid * 16 + 8 + j] * b_eattn[j];
        bq_eff[tid] = s1;
        bk_eff[tid] = s2;
        cmv[tid]    = s3;
    }
}

// ---------------------------------------------------------------------------
// Wave-per-row 8-head dot from bf16 features, transpose-butterfly reduce.
// ---------------------------------------------------------------------------
__global__ __launch_bounds__(256) void rowdot8_bf(
    const unsigned short* __restrict__ feat, const float* __restrict__ weff,
    const float* __restrict__ beff, float* __restrict__ out, int N)
{
    int gw   = (blockIdx.x * blockDim.x + threadIdx.x) >> 6;
    int lane = threadIdx.x & 63;
    if (gw >= N) return;
    int ch = lane * 2;
    unsigned int u = *(const unsigned int*)&feat[(long)gw * 128 + ch];
    float x0 = bflo(u), x1 = bfhi(u);
    float part[8];
#pragma unroll
    for (int h = 0; h < 8; ++h)
        part[h] = x0 * weff[h * 128 + ch] + x1 * weff[h * 128 + ch + 1];
    int b0 = lane & 1, b1 = (lane >> 1) & 1, b2 = (lane >> 2) & 1;
    float u0 = (b0 ? part[1] : part[0]) + __shfl_xor(b0 ? part[0] : part[1], 1);
    float u1 = (b0 ? part[3] : part[2]) + __shfl_xor(b0 ? part[2] : part[3], 1);
    float u2 = (b0 ? part[5] : part[4]) + __shfl_xor(b0 ? part[4] : part[5], 1);
    float u3 = (b0 ? part[7] : part[6]) + __shfl_xor(b0 ? part[6] : part[7], 1);
    float w0 = (b1 ? u1 : u0) + __shfl_xor(b1 ? u0 : u1, 2);
    float w1 = (b1 ? u3 : u2) + __shfl_xor(b1 ? u2 : u3, 2);
    float ts = (b2 ? w1 : w0) + __shfl_xor(b2 ? w0 : w1, 4);
    ts += __shfl_xor(ts, 8);
    ts += __shfl_xor(ts, 16);
    ts += __shfl_xor(ts, 32);
    if (lane < 8) out[(long)gw * 8 + lane] = ts + beff[lane];
}

// ---------------------------------------------------------------------------
// CSR build: histogram -> two-level scan -> scatter
// ---------------------------------------------------------------------------
__global__ void hist_kernel(const int* __restrict__ dst_idx, int* __restrict__ cnt)
{
    int e = blockIdx.x * blockDim.x + threadIdx.x;
    if (e < NE) atomicAdd(&cnt[dst_idx[e]], 1);
}

__global__ __launch_bounds__(256) void blocksum_kernel(const int* __restrict__ cnt,
                                                       int* __restrict__ bsum)
{
    __shared__ int sm[256];
    int b = blockIdx.x, t = threadIdx.x;
    int s = 0;
    for (int i = t; i < SCAN_CHUNK; i += 256) {
        int idx = b * SCAN_CHUNK + i;
        if (idx < N_DST) s += cnt[idx];
    }
    sm[t] = s; __syncthreads();
    for (int off = 128; off > 0; off >>= 1) {
        if (t < off) sm[t] += sm[t + off];
        __syncthreads();
    }
    if (t == 0) bsum[b] = sm[0];
}

__global__ void scanoff_kernel(const int* __restrict__ bsum, int* __restrict__ boff)
{
    if (threadIdx.x == 0) {
        int r = 0;
        for (int i = 0; i < NSCAN; ++i) { boff[i] = r; r += bsum[i]; }
    }
}

__global__ __launch_bounds__(256) void rowstart_kernel(
    const int* __restrict__ cnt, const int* __restrict__ boff,
    int* __restrict__ row_start, int* __restrict__ cursor)
{
    __shared__ int sm[256];
    int b = blockIdx.x, t = threadIdx.x;
    int base = b * SCAN_CHUNK + t * 4;
    int c[4]; int tot = 0;
#pragma unroll
    for (int j = 0; j < 4; ++j) {
        int idx = base + j;
        c[j] = (idx < N_DST) ? cnt[idx] : 0;
        tot += c[j];
    }
    sm[t] = tot; __syncthreads();
    for (int off = 1; off < 256; off <<= 1) {
        int v = (t >= off) ? sm[t - off] : 0;
        __syncthreads();
        sm[t] += v;
        __syncthreads();
    }
    int run = sm[t] - tot + boff[b];
#pragma unroll
    for (int j = 0; j < 4; ++j) {
        int idx = base + j;
        if (idx < N_DST) { row_start[idx] = run; cursor[idx] = run; run += c[j]; }
    }
    if (b == 0 && t == 0) row_start[N_DST] = NE;
}

__global__ void scatter_kernel(const int* __restrict__ dst_idx,
                               int* __restrict__ cursor, int* __restrict__ eorder)
{
    int e = blockIdx.x * blockDim.x + threadIdx.x;
    if (e >= NE) return;
    int pos = atomicAdd(&cursor[dst_idx[e]], 1);
    eorder[pos] = e;
}

// ---------------------------------------------------------------------------
// Mega-fused gather v2: one wave per dst. z = P * esf (precomputed exps);
// Wcomb-folded temp path; transpose-butterfly reduce (10 shfl); LN epilogue.
// ---------------------------------------------------------------------------
__global__ __launch_bounds__(256) void fused_gather2(
    const int* __restrict__ row_start, const int* __restrict__ eorder,
    const int* __restrict__ src_idx,
    const unsigned short* __restrict__ Pb, const unsigned short* __restrict__ esfb,
    const unsigned short* __restrict__ vb,
    const float* __restrict__ aq, const float* __restrict__ ak,
    const float* __restrict__ Wcomb, const float* __restrict__ cmv,
    const float* __restrict__ W_merge,
    const float* __restrict__ ln_gamma, const float* __restrict__ ln_beta,
    float* __restrict__ out)
{
    int gw   = (blockIdx.x * blockDim.x + threadIdx.x) >> 6;
    int lane = threadIdx.x & 63;
    if (gw >= N_DST) return;
    const int dst = gw;
    const int r0 = row_start[dst], r1 = row_start[dst + 1];
    const int ch = lane * 2;
    const int hl = lane & 7;
    const int g  = lane >> 3;
    const float rsc = 0.17677669529663687f;   // 1/sqrt(32)

    float wc0[8], wc1[8];
#pragma unroll
    for (int h = 0; h < 8; ++h) {
        wc0[h] = Wcomb[h * 128 + ch];
        wc1[h] = Wcomb[h * 128 + ch + 1];
    }
    const float wself = W_merge[g * 16 + hl];
    const float cmg   = cmv[g];
    const float aqh   = aq[(long)dst * 8 + hl];

    // ---- pass 1: denominators ----
    float s1x = 0.f, s1y = 0.f, s2l = 0.f;
    int eo = 0, src = 0;
    if (r0 < r1) { eo = eorder[r0]; src = src_idx[eo]; }
    for (int j = r0; j < r1; ++j) {
        int eo_n = 0, src_n = 0;
        if (j + 1 < r1) { eo_n = eorder[j + 1]; src_n = src_idx[eo_n]; }
        unsigned int pe = *(const unsigned int*)&Pb[(long)eo * 128 + ch];
        unsigned int se = *(const unsigned int*)&esfb[(long)src * 128 + ch];
        float akh = ak[(long)src * 8 + hl];
        s1x += bflo(pe) * bflo(se);
        s1y += bfhi(pe) * bfhi(se);
        s2l += expf((akh + aqh) * rsc);
        eo = eo_n; src = src_n;
    }
    const float i1x = 1.0f / s1x, i1y = 1.0f / s1y, i2 = 1.0f / s2l;

    // ---- pass 2: attention + aggregate ----
    float ax = 0.f, ay = 0.f, az = 0.f, aw = 0.f;
    if (r0 < r1) { eo = eorder[r0]; src = src_idx[eo]; }
    for (int j = r0; j < r1; ++j) {
        int eo_n = 0, src_n = 0;
        if (j + 1 < r1) { eo_n = eorder[j + 1]; src_n = src_idx[eo_n]; }
        unsigned int pe = *(const unsigned int*)&Pb[(long)eo * 128 + ch];
        unsigned int se = *(const unsigned int*)&esfb[(long)src * 128 + ch];
        float akh = ak[(long)src * 8 + hl];
        uint2 vv = *(const uint2*)&vb[(long)src * 256 + lane * 4];
        float t0 = bflo(pe) * bflo(se) * i1x;
        float t1 = bfhi(pe) * bfhi(se) * i1y;
        float part[8];
#pragma unroll
        for (int h = 0; h < 8; ++h) part[h] = t0 * wc0[h] + t1 * wc1[h];
        // transpose-butterfly: 8 values over 64 lanes in 10 shfl
        int b0 = lane & 1, b1 = (lane >> 1) & 1, b2 = (lane >> 2) & 1;
        float u0 = (b0 ? part[1] : part[0]) + __shfl_xor(b0 ? part[0] : part[1], 1);
        float u1 = (b0 ? part[3] : part[2]) + __shfl_xor(b0 ? part[2] : part[3], 1);
        float u2 = (b0 ? part[5] : part[4]) + __shfl_xor(b0 ? part[4] : part[5], 1);
        float u3 = (b0 ? part[7] : part[6]) + __shfl_xor(b0 ? part[6] : part[7], 1);
        float w0 = (b1 ? u1 : u0) + __shfl_xor(b1 ? u0 : u1, 2);
        float w1 = (b1 ? u3 : u2) + __shfl_xor(b1 ? u2 : u3, 2);
        float ts = (b2 ? w1 : w0) + __shfl_xor(b2 ? w0 : w1, 4);
        ts += __shfl_xor(ts, 8);
        ts += __shfl_xor(ts, 16);
        ts += __shfl_xor(ts, 32);
        // self part: group-local 3-shfl reduce (head g = lane>>3)
        float sa = expf((akh + aqh) * rsc) * i2;
        float ms = wself * sa;
        ms += __shfl_xor(ms, 1);
        ms += __shfl_xor(ms, 2);
        ms += __shfl_xor(ms, 4);
        float mm = cmg + ms + __shfl(ts, g);
        ax += mm * bflo(vv.x); ay += mm * bfhi(vv.x);
        az += mm * bflo(vv.y); aw += mm * bfhi(vv.y);
        eo = eo_n; src = src_n;
    }

    // ---- LayerNorm epilogue ----
    float s = ax + ay + az + aw;
    float q = ax * ax + ay * ay + az * az + aw * aw;
#pragma unroll
    for (int off = 32; off > 0; off >>= 1) {
        s += __shfl_xor(s, off);
        q += __shfl_xor(q, off);
    }
    float mu  = s * (1.0f / 256.0f);
    float var = q * (1.0f / 256.0f) - mu * mu;
    float inv = rsqrtf(var + 1e-5f);
    float4 gg = *(const float4*)&ln_gamma[lane * 4];
    float4 bb = *(const float4*)&ln_beta[lane * 4];
    float4 o;
    o.x = (ax - mu) * inv * gg.x + bb.x;
    o.y = (ay - mu) * inv * gg.y + bb.y;
    o.z = (az - mu) * inv * gg.z + bb.z;
    o.w = (aw - mu) * inv * gg.w + bb.w;
    *(float4*)&out[(long)dst * 256 + lane * 4] = o;
}

// ---------------------------------------------------------------------------
extern "C" void kernel_launch(void* const* d_in, const int* in_sizes, int n_in,
                              void* d_out, int out_size, void* d_ws, size_t ws_size,
                              hipStream_t stream)
{
    const float* x_user        = (const float*)d_in[0];
    const float* x_item        = (const float*)d_in[1];
    const float* node_emb_user = (const float*)d_in[2];
    const float* edge_emb      = (const float*)d_in[3];
    const float* edge_feats    = (const float*)d_in[4];
    const int*   src_idx       = (const int*)d_in[5];
    const int*   dst_idx       = (const int*)d_in[6];
    const float* W_nf_user     = (const float*)d_in[7];
    const float* b_nf_user     = (const float*)d_in[8];
    const float* W_nf_item     = (const float*)d_in[9];
    const float* b_nf_item     = (const float*)d_in[10];
    const float* W_ef          = (const float*)d_in[11];
    const float* b_ef          = (const float*)d_in[12];
    const float* W_eattn       = (const float*)d_in[13];
    const float* b_eattn       = (const float*)d_in[14];
    const float* W_merge       = (const float*)d_in[15];
    const float* b_merge       = (const float*)d_in[16];
    const float* W_q           = (const float*)d_in[17];
    const float* b_q           = (const float*)d_in[18];
    const float* W_k           = (const float*)d_in[19];
    const float* b_k           = (const float*)d_in[20];
    const float* W_v           = (const float*)d_in[21];
    const float* b_v           = (const float*)d_in[22];
    const float* W_na_user     = (const float*)d_in[23];
    const float* W_na_item     = (const float*)d_in[24];
    const float* ln_gamma      = (const float*)d_in[25];
    const float* ln_beta       = (const float*)d_in[26];

    unsigned short* us   = (unsigned short*)d_ws;
    unsigned short* sf_b  = us;                    // 25,600,000  bf16 src_feat
    unsigned short* esf_b = sf_b + 25600000;       // 25,600,000  bf16 exp(src_feat)
    unsigned short* dsf_b = esf_b + 25600000;      // 12,800,000  bf16 dst_feat
    unsigned short* P_b   = dsf_b + 12800000;      // 51,200,000  bf16 exp(ef)
    unsigned short* v_b   = P_b + 51200000;        // 51,200,000  bf16 v
    float* fz     = (float*)(v_b + 51200000);
    float* aq     = fz;                            // 800,000
    float* ak     = aq + 800000;                   // 1,600,000
    float* wq_eff = ak + 1600000;                  // 1024
    float* wk_eff = wq_eff + 1024;                 // 1024
    float* bq_eff = wk_eff + 1024;                 // 16
    float* bk_eff = bq_eff + 16;                   // 16
    float* Wcomb  = bk_eff + 16;                   // 1024
    float* cmv    = Wcomb + 1024;                  // 8
    int*   cnt       = (int*)(cmv + 8);            // N_DST
    int*   bsum      = cnt + N_DST;                // 128
    int*   boff      = bsum + 128;                 // 128
    int*   row_start = boff + 128;                 // N_DST + 1
    int*   cursor    = row_start + N_DST + 1;      // N_DST
    int*   eorder    = cursor + N_DST;             // NE
    // W fragment buffers (16B-aligned for dwordx4 loads)
    unsigned short* wub = (unsigned short*)(((uintptr_t)(eorder + NE) + 15) & ~(uintptr_t)15);
    unsigned short* wib = wub + 128 * 320;
    unsigned short* web = wib + 128 * 224;
    unsigned short* wvb = web + 128 * 64;
    size_t needed = (size_t)((char*)(wvb + 256 * 128) - (char*)d_ws);
    if (ws_size < needed) {
        fprintf(stderr, "kernel_launch: ws_size %zu < needed %zu\n", ws_size, needed);
        return;
    }

    hipMemsetAsync(cnt, 0, N_DST * sizeof(int), stream);

    eff_setup<<<1, 256, 0, stream>>>(W_q, b_q, W_na_item, W_k, b_k, W_na_user,
                                     W_merge, b_merge, W_eattn, b_eattn,
                                     wq_eff, bq_eff, wk_eff, bk_eff, Wcomb, cmv);

    // weight pre-conversion to bf16 B-fragment layout (padded K)
    wconv_frag<<<64, 256, 0, stream>>>(W_nf_user, wub, 128, 300, 320);
    wconv_frag<<<64, 256, 0, stream>>>(W_nf_item, wib, 128, 200, 224);
    wconv_frag<<<32, 256, 0, stream>>>(W_ef,      web, 128,  64,  64);
    wconv_frag<<<64, 256, 0, stream>>>(W_v,       wvb, 256, 128, 128);

    // GEMM1: src_feat = x_user@W_nf_user^T + b + node_emb + edge_emb -> sf_b & esf_b
    gemm_batch<false, 300, 320, 2, 8, 10><<<dim3(1, 1563), 256, 0, stream>>>(
        x_user, wub, b_nf_user, node_emb_user, edge_emb,
        sf_b, esf_b, N_SRC, 128);
    // GEMM2: dst_feat = x_item@W_nf_item^T + b + edge_emb -> dsf_b
    gemm_batch<false, 200, 224, 1, 8, 14><<<dim3(1, 782), 256, 0, stream>>>(
        x_item, wib, b_nf_item, nullptr, edge_emb,
        dsf_b, nullptr, N_DST, 128);
    // GEMM3: P = exp(edge_feats@W_ef^T + b_ef) -> P_b
    gemm_batch<false, 64, 64, 1, 8, 8><<<dim3(1, 3125), 256, 0, stream>>>(
        edge_feats, web, b_ef, nullptr, nullptr,
        nullptr, P_b, NE, 128);
    // GEMM4: v = sf@W_v^T + b_v -> v_b (A bf16; C=256 split over grid.x=2)
    gemm_batch<true, 128, 128, 1, 8, 8><<<dim3(2, 1563), 256, 0, stream>>>(
        sf_b, wvb, b_v, nullptr, nullptr,
        v_b, nullptr, N_SRC, 256);

    // aq / ak via folded weights
    rowdot8_bf<<<25000, 256, 0, stream>>>(dsf_b, wq_eff, bq_eff, aq, N_DST);
    rowdot8_bf<<<50000, 256, 0, stream>>>(sf_b, wk_eff, bk_eff, ak, N_SRC);

    // CSR build
    hist_kernel<<<1563, 256, 0, stream>>>(dst_idx, cnt);
    blocksum_kernel<<<NSCAN, 256, 0, stream>>>(cnt, bsum);
    scanoff_kernel<<<1, 64, 0, stream>>>(bsum, boff);
    rowstart_kernel<<<NSCAN, 256, 0, stream>>>(cnt, boff, row_start, cursor);
    scatter_kernel<<<1563, 256, 0, stream>>>(dst_idx, cursor, eorder);

    // mega-fused gather + LN
    fused_gather2<<<25000, 256, 0, stream>>>(
        row_start, eorder, src_idx, P_b, esf_b, v_b, aq, ak,
        Wcomb, cmv, W_merge, ln_gamma, ln_beta, (float*)d_out);
}

// Round 9
// 814.190 us; speedup vs baseline: 1.1669x; 1.1669x over previous
//
#include <hip/hip_runtime.h>
#include <math.h>
#include <stdio.h>
#include <stdint.h>

#define N_SRC 200000
#define N_DST 100000
#define NE    400000
// IN=128, H=8, D=32, H*D=256

#define SCAN_CHUNK 1024
#define NSCAN ((N_DST + SCAN_CHUNK - 1) / SCAN_CHUNK)   // 98

typedef short bf16x8 __attribute__((ext_vector_type(8)));
typedef float f32x4 __attribute__((ext_vector_type(4)));

__device__ __forceinline__ float bflo(unsigned int u) { return __uint_as_float(u << 16); }
__device__ __forceinline__ float bfhi(unsigned int u) { return __uint_as_float(u & 0xFFFF0000u); }
__device__ __forceinline__ unsigned short f2bf(float f) {
    unsigned int u = __float_as_uint(f);
    u += 0x7FFFu + ((u >> 16) & 1u);       // round-to-nearest-even
    return (unsigned short)(u >> 16);
}
// pack two f32 -> (bf16(f1)<<16)|bf16(f0) by truncation: single v_perm_b32
__device__ __forceinline__ unsigned int packbf(float f0, float f1) {
    return __builtin_amdgcn_perm(__float_as_uint(f1), __float_as_uint(f0), 0x07060302u);
}
// async global->LDS DMA, 16 bytes per lane (dest = wave-uniform base + lane*16)
__device__ __forceinline__ void gl2lds(const void* g, void* l) {
    __builtin_amdgcn_global_load_lds(
        (const __attribute__((address_space(1))) unsigned int*)g,
        (__attribute__((address_space(3))) unsigned int*)l, 16, 0, 0);
}

// ---------------------------------------------------------------------------
// m97-style GEMM: global_load_lds staging + counted-vmcnt double buffer.
// out[n][c] = sum_k A[n][k]*W[c][k] (+bias+add_c+add_n).
// - A staged as RAW F32 via gl_lds (16B/lane, zero VGPR cost, DMA queue holds
//   HBM latency); converted to bf16 only at fragment-build (4 v_perm/frag).
// - B fragments reordered [ks][n] -> each K-step's 8KB is contiguous; staged
//   into LDS once per block-step (shared by all 4 waves).
// - Loop: issue stage(ks+1) -> s_waitcnt vmcnt(NV) (counted: next-step loads
//   NEVER drained) -> s_barrier -> frags+MFMA -> lgkmcnt(0)+s_barrier.
// - K tail: lanes whose k-chunk exceeds K clamp gaddr to row base; the junk
//   is annihilated because wconv_frag zero-pads B for k>=K.
// A: f32 [N][K] (ABF=false) or bf16 [N][K] (ABF=true, K==KP).
// ---------------------------------------------------------------------------
template<bool ABF, int K, int KP, int NT>
__global__ __launch_bounds__(256) void gemm_glds(
    const void* __restrict__ Ap, const unsigned short* __restrict__ Wf,
    const float* __restrict__ bias, const float* __restrict__ add_n,
    const float* __restrict__ add_c,
    unsigned short* __restrict__ out_lin, unsigned short* __restrict__ out_exp,
    int N, int C)
{
    constexpr int KST   = KP / 32;
    constexpr int ARB   = ABF ? 64 : 128;      // LDS A row bytes (32 elems)
    constexpr int ASTEP = 128 * ARB;           // 8KB (bf16) or 16KB (f32)
    __shared__ __align__(16) char As[2 * ASTEP];
    __shared__ __align__(16) char Bs[2 * 8192];

    const int tid  = threadIdx.x;
    const int lane = tid & 63;
    const int wv   = tid >> 6;
    const int fr   = lane & 15;
    const int fq   = lane >> 4;
    const int row0 = blockIdx.y * 128;
    const int nb0  = blockIdx.x * NT;
    const int NTC  = C / 16;

    f32x4 acc[2][NT];
#pragma unroll
    for (int m = 0; m < 2; ++m)
#pragma unroll
        for (int n = 0; n < NT; ++n) acc[m][n] = (f32x4){0.f, 0.f, 0.f, 0.f};

    auto stage = [&](int buf, int ks) {
        char* ab = As + buf * ASTEP;
        char* bb = Bs + buf * 8192;
        if (ABF) {
            const char* Ab = (const char*)Ap;
#pragma unroll
            for (int q = 0; q < 2; ++q) {
                int i   = wv * 2 + q;
                int row = i * 16 + (lane >> 2);
                int rr  = row0 + row; if (rr >= N) rr = N - 1;
                gl2lds(Ab + ((long)rr * K + ks * 32 + (lane & 3) * 8) * 2,
                       ab + i * 1024 + lane * 16);
            }
        } else {
            const char* Af = (const char*)Ap;
#pragma unroll
            for (int q = 0; q < 4; ++q) {
                int i   = wv * 4 + q;
                int row = i * 8 + (lane >> 3);
                int rr  = row0 + row; if (rr >= N) rr = N - 1;
                int kk  = ks * 32 + (lane & 7) * 4;
                long off = (long)rr * K + ((kk + 4 <= K) ? kk : 0);
                gl2lds(Af + off * 4, ab + i * 1024 + lane * 16);
            }
        }
        const char* wbase = (const char*)Wf + ((size_t)ks * NTC + nb0) * 1024;
#pragma unroll
        for (int q = 0; q < 2; ++q) {
            int i = wv * 2 + q;
            gl2lds(wbase + i * 1024 + lane * 16, bb + i * 1024 + lane * 16);
        }
    };

    stage(0, 0);
    for (int ks = 0; ks < KST; ++ks) {
        const int cur = ks & 1;
        if (ks + 1 < KST) {
            stage(cur ^ 1, ks + 1);
            if (ABF) asm volatile("s_waitcnt vmcnt(4)" ::: "memory");
            else     asm volatile("s_waitcnt vmcnt(6)" ::: "memory");
        } else {
            asm volatile("s_waitcnt vmcnt(0)" ::: "memory");
        }
        __builtin_amdgcn_s_barrier();

        const char* ab = As + cur * ASTEP;
        const char* bb = Bs + cur * 8192;
        bf16x8 a0, a1;
        if (ABF) {
            a0 = *(const bf16x8*)(ab + (wv * 32 +      fr) * 64 + fq * 16);
            a1 = *(const bf16x8*)(ab + (wv * 32 + 16 + fr) * 64 + fq * 16);
        } else {
            float4 f0 = *(const float4*)(ab + (wv * 32 +      fr) * 128 + fq * 32);
            float4 f1 = *(const float4*)(ab + (wv * 32 +      fr) * 128 + fq * 32 + 16);
            float4 f2 = *(const float4*)(ab + (wv * 32 + 16 + fr) * 128 + fq * 32);
            float4 f3 = *(const float4*)(ab + (wv * 32 + 16 + fr) * 128 + fq * 32 + 16);
            uint4 u0, u1;
            u0.x = packbf(f0.x, f0.y); u0.y = packbf(f0.z, f0.w);
            u0.z = packbf(f1.x, f1.y); u0.w = packbf(f1.z, f1.w);
            u1.x = packbf(f2.x, f2.y); u1.y = packbf(f2.z, f2.w);
            u1.z = packbf(f3.x, f3.y); u1.w = packbf(f3.z, f3.w);
            a0 = *(bf16x8*)&u0;
            a1 = *(bf16x8*)&u1;
        }
        uint4 pb[NT];
#pragma unroll
        for (int n = 0; n < NT; ++n)
            pb[n] = *(const uint4*)(bb + n * 1024 + lane * 16);
#pragma unroll
        for (int n = 0; n < NT; ++n) {
            acc[0][n] = __builtin_amdgcn_mfma_f32_16x16x32_bf16(a0, *(bf16x8*)&pb[n], acc[0][n], 0, 0, 0);
            acc[1][n] = __builtin_amdgcn_mfma_f32_16x16x32_bf16(a1, *(bf16x8*)&pb[n], acc[1][n], 0, 0, 0);
        }
        asm volatile("s_waitcnt lgkmcnt(0)" ::: "memory");
        __builtin_amdgcn_s_barrier();
    }

    // epilogue: D col = lane&15, row = (lane>>4)*4 + reg (measured m89/m91)
    float bc[NT];
#pragma unroll
    for (int n = 0; n < NT; ++n) {
        int col = (nb0 + n) * 16 + fr;
        float b = 0.f;
        if (bias)  b += bias[col];
        if (add_c) b += add_c[col];
        bc[n] = b;
    }
#pragma unroll
    for (int m = 0; m < 2; ++m) {
#pragma unroll
        for (int j = 0; j < 4; ++j) {
            int row = row0 + wv * 32 + m * 16 + fq * 4 + j;
            if (row >= N) continue;
#pragma unroll
            for (int n = 0; n < NT; ++n) {
                int col = (nb0 + n) * 16 + fr;
                float v = acc[m][n][j] + bc[n];
                if (add_n) v += add_n[(long)row * C + col];
                long o = (long)row * C + col;
                if (out_lin) out_lin[o] = f2bf(v);
                if (out_exp) out_exp[o] = f2bf(expf(v));
            }
        }
    }
}

// ---------------------------------------------------------------------------
// Weight f32 [C][K] -> bf16 B-fragment layout, [ks][n] major so each K-step
// is one contiguous (C/16)*1KB block; zero-padded to Kp (KST=Kp/32):
// dst[((ks*NTC + n)*64 + l)*8 + j] = W[n*16 + (l&15)][ks*32 + (l>>4)*8 + j]
// ---------------------------------------------------------------------------
__global__ void wconv_frag(const float* __restrict__ src, unsigned short* __restrict__ dst,
                           int C, int K, int Kp)
{
    int NTC = C >> 4;
    int total = C * Kp;
    for (int i = blockIdx.x * blockDim.x + threadIdx.x; i < total; i += gridDim.x * blockDim.x) {
        int j  = i & 7;
        int l  = (i >> 3) & 63;
        int t  = i >> 9;
        int n  = t % NTC;
        int ks = t / NTC;
        int col = n * 16 + (l & 15);
        int k   = ks * 32 + ((l >> 4) << 3) + j;
        dst[i] = (k < K) ? f2bf(src[(long)col * K + k]) : (unsigned short)0;
    }
}

// ---------------------------------------------------------------------------
// Setup: fold W_na into Q/K (wq_eff/wk_eff [8][128]), fold W_merge x W_eattn
// into Wcomb [8][128], cm[8] = b_merge + W_merge[:,8:] . b_eattn
// ---------------------------------------------------------------------------
__global__ void eff_setup(const float* __restrict__ Wq, const float* __restrict__ bq,
                          const float* __restrict__ na_item,
                          const float* __restrict__ Wk, const float* __restrict__ bk,
                          const float* __restrict__ na_user,
                          const float* __restrict__ W_merge, const float* __restrict__ b_merge,
                          const float* __restrict__ W_eattn, const float* __restrict__ b_eattn,
                          float* __restrict__ wq_eff, float* __restrict__ bq_eff,
                          float* __restrict__ wk_eff, float* __restrict__ bk_eff,
                          float* __restrict__ Wcomb, float* __restrict__ cmv)
{
    int tid = threadIdx.x;
    for (int idx = tid; idx < 1024; idx += 256) {
        int h = idx >> 7, k = idx & 127;
        float s1 = 0.f, s2 = 0.f, s3 = 0.f;
        for (int d = 0; d < 32; ++d) {
            s1 += Wq[(h * 32 + d) * 128 + k] * na_item[d];
            s2 += Wk[(h * 32 + d) * 128 + k] * na_user[d];
        }
        for (int j = 0; j < 8; ++j)
            s3 += W_merge[h * 16 + 8 + j] * W_eattn[j * 128 + k];
        wq_eff[idx] = s1;
        wk_eff[idx] = s2;
        Wcomb[idx]  = s3;
    }
    if (tid < 8) {
        float s1 = 0.f, s2 = 0.f, s3 = b_merge[tid];
        for (int d = 0; d < 32; ++d) {
            s1 += bq[tid * 32 + d] * na_item[d];
            s2 += bk[tid * 32 + d] * na_user[d];
        }
        for (int j = 0; j < 8; ++j) s3 += W_merge[tid * 16 + 8 + j] * b_eattn[j];
        bq_eff[tid] = s1;
        bk_eff[tid] = s2;
        cmv[tid]    = s3;
    }
}

// ---------------------------------------------------------------------------
// Wave-per-row 8-head dot from bf16 features, transpose-butterfly reduce.
// ---------------------------------------------------------------------------
__global__ __launch_bounds__(256) void rowdot8_bf(
    const unsigned short* __restrict__ feat, const float* __restrict__ weff,
    const float* __restrict__ beff, float* __restrict__ out, int N)
{
    int gw   = (blockIdx.x * blockDim.x + threadIdx.x) >> 6;
    int lane = threadIdx.x & 63;
    if (gw >= N) return;
    int ch = lane * 2;
    unsigned int u = *(const unsigned int*)&feat[(long)gw * 128 + ch];
    float x0 = bflo(u), x1 = bfhi(u);
    float part[8];
#pragma unroll
    for (int h = 0; h < 8; ++h)
        part[h] = x0 * weff[h * 128 + ch] + x1 * weff[h * 128 + ch + 1];
    int b0 = lane & 1, b1 = (lane >> 1) & 1, b2 = (lane >> 2) & 1;
    float u0 = (b0 ? part[1] : part[0]) + __shfl_xor(b0 ? part[0] : part[1], 1);
    float u1 = (b0 ? part[3] : part[2]) + __shfl_xor(b0 ? part[2] : part[3], 1);
    float u2 = (b0 ? part[5] : part[4]) + __shfl_xor(b0 ? part[4] : part[5], 1);
    float u3 = (b0 ? part[7] : part[6]) + __shfl_xor(b0 ? part[6] : part[7], 1);
    float w0 = (b1 ? u1 : u0) + __shfl_xor(b1 ? u0 : u1, 2);
    float w1 = (b1 ? u3 : u2) + __shfl_xor(b1 ? u2 : u3, 2);
    float ts = (b2 ? w1 : w0) + __shfl_xor(b2 ? w0 : w1, 4);
    ts += __shfl_xor(ts, 8);
    ts += __shfl_xor(ts, 16);
    ts += __shfl_xor(ts, 32);
    if (lane < 8) out[(long)gw * 8 + lane] = ts + beff[lane];
}

// ---------------------------------------------------------------------------
// CSR build: histogram -> two-level scan -> scatter
// ---------------------------------------------------------------------------
__global__ void hist_kernel(const int* __restrict__ dst_idx, int* __restrict__ cnt)
{
    int e = blockIdx.x * blockDim.x + threadIdx.x;
    if (e < NE) atomicAdd(&cnt[dst_idx[e]], 1);
}

__global__ __launch_bounds__(256) void blocksum_kernel(const int* __restrict__ cnt,
                                                       int* __restrict__ bsum)
{
    __shared__ int sm[256];
    int b = blockIdx.x, t = threadIdx.x;
    int s = 0;
    for (int i = t; i < SCAN_CHUNK; i += 256) {
        int idx = b * SCAN_CHUNK + i;
        if (idx < N_DST) s += cnt[idx];
    }
    sm[t] = s; __syncthreads();
    for (int off = 128; off > 0; off >>= 1) {
        if (t < off) sm[t] += sm[t + off];
        __syncthreads();
    }
    if (t == 0) bsum[b] = sm[0];
}

__global__ void scanoff_kernel(const int* __restrict__ bsum, int* __restrict__ boff)
{
    if (threadIdx.x == 0) {
        int r = 0;
        for (int i = 0; i < NSCAN; ++i) { boff[i] = r; r += bsum[i]; }
    }
}

__global__ __launch_bounds__(256) void rowstart_kernel(
    const int* __restrict__ cnt, const int* __restrict__ boff,
    int* __restrict__ row_start, int* __restrict__ cursor)
{
    __shared__ int sm[256];
    int b = blockIdx.x, t = threadIdx.x;
    int base = b * SCAN_CHUNK + t * 4;
    int c[4]; int tot = 0;
#pragma unroll
    for (int j = 0; j < 4; ++j) {
        int idx = base + j;
        c[j] = (idx < N_DST) ? cnt[idx] : 0;
        tot += c[j];
    }
    sm[t] = tot; __syncthreads();
    for (int off = 1; off < 256; off <<= 1) {
        int v = (t >= off) ? sm[t - off] : 0;
        __syncthreads();
        sm[t] += v;
        __syncthreads();
    }
    int run = sm[t] - tot + boff[b];
#pragma unroll
    for (int j = 0; j < 4; ++j) {
        int idx = base + j;
        if (idx < N_DST) { row_start[idx] = run; cursor[idx] = run; run += c[j]; }
    }
    if (b == 0 && t == 0) row_start[N_DST] = NE;
}

__global__ void scatter_kernel(const int* __restrict__ dst_idx,
                               int* __restrict__ cursor, int* __restrict__ eorder)
{
    int e = blockIdx.x * blockDim.x + threadIdx.x;
    if (e >= NE) return;
    int pos = atomicAdd(&cursor[dst_idx[e]], 1);
    eorder[pos] = e;
}

// ---------------------------------------------------------------------------
// Mega-fused gather v2: one wave per dst. z = P * esf (precomputed exps);
// Wcomb-folded temp path; transpose-butterfly reduce (10 shfl); LN epilogue.
// ---------------------------------------------------------------------------
__global__ __launch_bounds__(256) void fused_gather2(
    const int* __restrict__ row_start, const int* __restrict__ eorder,
    const int* __restrict__ src_idx,
    const unsigned short* __restrict__ Pb, const unsigned short* __restrict__ esfb,
    const unsigned short* __restrict__ vb,
    const float* __restrict__ aq, const float* __restrict__ ak,
    const float* __restrict__ Wcomb, const float* __restrict__ cmv,
    const float* __restrict__ W_merge,
    const float* __restrict__ ln_gamma, const float* __restrict__ ln_beta,
    float* __restrict__ out)
{
    int gw   = (blockIdx.x * blockDim.x + threadIdx.x) >> 6;
    int lane = threadIdx.x & 63;
    if (gw >= N_DST) return;
    const int dst = gw;
    const int r0 = row_start[dst], r1 = row_start[dst + 1];
    const int ch = lane * 2;
    const int hl = lane & 7;
    const int g  = lane >> 3;
    const float rsc = 0.17677669529663687f;   // 1/sqrt(32)

    float wc0[8], wc1[8];
#pragma unroll
    for (int h = 0; h < 8; ++h) {
        wc0[h] = Wcomb[h * 128 + ch];
        wc1[h] = Wcomb[h * 128 + ch + 1];
    }
    const float wself = W_merge[g * 16 + hl];
    const float cmg   = cmv[g];
    const float aqh   = aq[(long)dst * 8 + hl];

    // ---- pass 1: denominators ----
    float s1x = 0.f, s1y = 0.f, s2l = 0.f;
    int eo = 0, src = 0;
    if (r0 < r1) { eo = eorder[r0]; src = src_idx[eo]; }
    for (int j = r0; j < r1; ++j) {
        int eo_n = 0, src_n = 0;
        if (j + 1 < r1) { eo_n = eorder[j + 1]; src_n = src_idx[eo_n]; }
        unsigned int pe = *(const unsigned int*)&Pb[(long)eo * 128 + ch];
        unsigned int se = *(const unsigned int*)&esfb[(long)src * 128 + ch];
        float akh = ak[(long)src * 8 + hl];
        s1x += bflo(pe) * bflo(se);
        s1y += bfhi(pe) * bfhi(se);
        s2l += expf((akh + aqh) * rsc);
        eo = eo_n; src = src_n;
    }
    const float i1x = 1.0f / s1x, i1y = 1.0f / s1y, i2 = 1.0f / s2l;

    // ---- pass 2: attention + aggregate ----
    float ax = 0.f, ay = 0.f, az = 0.f, aw = 0.f;
    if (r0 < r1) { eo = eorder[r0]; src = src_idx[eo]; }
    for (int j = r0; j < r1; ++j) {
        int eo_n = 0, src_n = 0;
        if (j + 1 < r1) { eo_n = eorder[j + 1]; src_n = src_idx[eo_n]; }
        unsigned int pe = *(const unsigned int*)&Pb[(long)eo * 128 + ch];
        unsigned int se = *(const unsigned int*)&esfb[(long)src * 128 + ch];
        float akh = ak[(long)src * 8 + hl];
        uint2 vv = *(const uint2*)&vb[(long)src * 256 + lane * 4];
        float t0 = bflo(pe) * bflo(se) * i1x;
        float t1 = bfhi(pe) * bfhi(se) * i1y;
        float part[8];
#pragma unroll
        for (int h = 0; h < 8; ++h) part[h] = t0 * wc0[h] + t1 * wc1[h];
        // transpose-butterfly: 8 values over 64 lanes in 10 shfl
        int b0 = lane & 1, b1 = (lane >> 1) & 1, b2 = (lane >> 2) & 1;
        float u0 = (b0 ? part[1] : part[0]) + __shfl_xor(b0 ? part[0] : part[1], 1);
        float u1 = (b0 ? part[3] : part[2]) + __shfl_xor(b0 ? part[2] : part[3], 1);
        float u2 = (b0 ? part[5] : part[4]) + __shfl_xor(b0 ? part[4] : part[5], 1);
        float u3 = (b0 ? part[7] : part[6]) + __shfl_xor(b0 ? part[6] : part[7], 1);
        float w0 = (b1 ? u1 : u0) + __shfl_xor(b1 ? u0 : u1, 2);
        float w1 = (b1 ? u3 : u2) + __shfl_xor(b1 ? u2 : u3, 2);
        float ts = (b2 ? w1 : w0) + __shfl_xor(b2 ? w0 : w1, 4);
        ts += __shfl_xor(ts, 8);
        ts += __shfl_xor(ts, 16);
        ts += __shfl_xor(ts, 32);
        // self part: group-local 3-shfl reduce (head g = lane>>3)
        float sa = expf((akh + aqh) * rsc) * i2;
        float ms = wself * sa;
        ms += __shfl_xor(ms, 1);
        ms += __shfl_xor(ms, 2);
        ms += __shfl_xor(ms, 4);
        float mm = cmg + ms + __shfl(ts, g);
        ax += mm * bflo(vv.x); ay += mm * bfhi(vv.x);
        az += mm * bflo(vv.y); aw += mm * bfhi(vv.y);
        eo = eo_n; src = src_n;
    }

    // ---- LayerNorm epilogue ----
    float s = ax + ay + az + aw;
    float q = ax * ax + ay * ay + az * az + aw * aw;
#pragma unroll
    for (int off = 32; off > 0; off >>= 1) {
        s += __shfl_xor(s, off);
        q += __shfl_xor(q, off);
    }
    float mu  = s * (1.0f / 256.0f);
    float var = q * (1.0f / 256.0f) - mu * mu;
    float inv = rsqrtf(var + 1e-5f);
    float4 gg = *(const float4*)&ln_gamma[lane * 4];
    float4 bb = *(const float4*)&ln_beta[lane * 4];
    float4 o;
    o.x = (ax - mu) * inv * gg.x + bb.x;
    o.y = (ay - mu) * inv * gg.y + bb.y;
    o.z = (az - mu) * inv * gg.z + bb.z;
    o.w = (aw - mu) * inv * gg.w + bb.w;
    *(float4*)&out[(long)dst * 256 + lane * 4] = o;
}

// ---------------------------------------------------------------------------
extern "C" void kernel_launch(void* const* d_in, const int* in_sizes, int n_in,
                              void* d_out, int out_size, void* d_ws, size_t ws_size,
                              hipStream_t stream)
{
    const float* x_user        = (const float*)d_in[0];
    const float* x_item        = (const float*)d_in[1];
    const float* node_emb_user = (const float*)d_in[2];
    const float* edge_emb      = (const float*)d_in[3];
    const float* edge_feats    = (const float*)d_in[4];
    const int*   src_idx       = (const int*)d_in[5];
    const int*   dst_idx       = (const int*)d_in[6];
    const float* W_nf_user     = (const float*)d_in[7];
    const float* b_nf_user     = (const float*)d_in[8];
    const float* W_nf_item     = (const float*)d_in[9];
    const float* b_nf_item     = (const float*)d_in[10];
    const float* W_ef          = (const float*)d_in[11];
    const float* b_ef          = (const float*)d_in[12];
    const float* W_eattn       = (const float*)d_in[13];
    const float* b_eattn       = (const float*)d_in[14];
    const float* W_merge       = (const float*)d_in[15];
    const float* b_merge       = (const float*)d_in[16];
    const float* W_q           = (const float*)d_in[17];
    const float* b_q           = (const float*)d_in[18];
    const float* W_k           = (const float*)d_in[19];
    const float* b_k           = (const float*)d_in[20];
    const float* W_v           = (const float*)d_in[21];
    const float* b_v           = (const float*)d_in[22];
    const float* W_na_user     = (const float*)d_in[23];
    const float* W_na_item     = (const float*)d_in[24];
    const float* ln_gamma      = (const float*)d_in[25];
    const float* ln_beta       = (const float*)d_in[26];

    unsigned short* us   = (unsigned short*)d_ws;
    unsigned short* sf_b  = us;                    // 25,600,000  bf16 src_feat
    unsigned short* esf_b = sf_b + 25600000;       // 25,600,000  bf16 exp(src_feat)
    unsigned short* dsf_b = esf_b + 25600000;      // 12,800,000  bf16 dst_feat
    unsigned short* P_b   = dsf_b + 12800000;      // 51,200,000  bf16 exp(ef)
    unsigned short* v_b   = P_b + 51200000;        // 51,200,000  bf16 v
    float* fz     = (float*)(v_b + 51200000);
    float* aq     = fz;                            // 800,000
    float* ak     = aq + 800000;                   // 1,600,000
    float* wq_eff = ak + 1600000;                  // 1024
    float* wk_eff = wq_eff + 1024;                 // 1024
    float* bq_eff = wk_eff + 1024;                 // 16
    float* bk_eff = bq_eff + 16;                   // 16
    float* Wcomb  = bk_eff + 16;                   // 1024
    float* cmv    = Wcomb + 1024;                  // 8
    int*   cnt       = (int*)(cmv + 8);            // N_DST
    int*   bsum      = cnt + N_DST;                // 128
    int*   boff      = bsum + 128;                 // 128
    int*   row_start = boff + 128;                 // N_DST + 1
    int*   cursor    = row_start + N_DST + 1;      // N_DST
    int*   eorder    = cursor + N_DST;             // NE
    // W fragment buffers (16B-aligned for gl_lds / dwordx4 loads)
    unsigned short* wub = (unsigned short*)(((uintptr_t)(eorder + NE) + 15) & ~(uintptr_t)15);
    unsigned short* wib = wub + 128 * 320;
    unsigned short* web = wib + 128 * 224;
    unsigned short* wvb = web + 128 * 64;
    size_t needed = (size_t)((char*)(wvb + 256 * 128) - (char*)d_ws);
    if (ws_size < needed) {
        fprintf(stderr, "kernel_launch: ws_size %zu < needed %zu\n", ws_size, needed);
        return;
    }

    hipMemsetAsync(cnt, 0, N_DST * sizeof(int), stream);

    eff_setup<<<1, 256, 0, stream>>>(W_q, b_q, W_na_item, W_k, b_k, W_na_user,
                                     W_merge, b_merge, W_eattn, b_eattn,
                                     wq_eff, bq_eff, wk_eff, bk_eff, Wcomb, cmv);

    // weight pre-conversion to bf16 B-fragment layout ([ks][n] major, padded K)
    wconv_frag<<<64, 256, 0, stream>>>(W_nf_user, wub, 128, 300, 320);
    wconv_frag<<<64, 256, 0, stream>>>(W_nf_item, wib, 128, 200, 224);
    wconv_frag<<<32, 256, 0, stream>>>(W_ef,      web, 128,  64,  64);
    wconv_frag<<<64, 256, 0, stream>>>(W_v,       wvb, 256, 128, 128);

    // GEMM1: src_feat = x_user@W_nf_user^T + b + node_emb + edge_emb -> sf_b & esf_b
    gemm_glds<false, 300, 320, 8><<<dim3(1, 1563), 256, 0, stream>>>(
        x_user, wub, b_nf_user, node_emb_user, edge_emb,
        sf_b, esf_b, N_SRC, 128);
    // GEMM2: dst_feat = x_item@W_nf_item^T + b + edge_emb -> dsf_b
    gemm_glds<false, 200, 224, 8><<<dim3(1, 782), 256, 0, stream>>>(
        x_item, wib, b_nf_item, nullptr, edge_emb,
        dsf_b, nullptr, N_DST, 128);
    // GEMM3: P = exp(edge_feats@W_ef^T + b_ef) -> P_b
    gemm_glds<false, 64, 64, 8><<<dim3(1, 3125), 256, 0, stream>>>(
        edge_feats, web, b_ef, nullptr, nullptr,
        nullptr, P_b, NE, 128);
    // GEMM4: v = sf@W_v^T + b_v -> v_b (A bf16; C=256 split over grid.x=2)
    gemm_glds<true, 128, 128, 8><<<dim3(2, 1563), 256, 0, stream>>>(
        sf_b, wvb, b_v, nullptr, nullptr,
        v_b, nullptr, N_SRC, 256);

    // aq / ak via folded weights
    rowdot8_bf<<<25000, 256, 0, stream>>>(dsf_b, wq_eff, bq_eff, aq, N_DST);
    rowdot8_bf<<<50000, 256, 0, stream>>>(sf_b, wk_eff, bk_eff, ak, N_SRC);

    // CSR build
    hist_kernel<<<1563, 256, 0, stream>>>(dst_idx, cnt);
    blocksum_kernel<<<NSCAN, 256, 0, stream>>>(cnt, bsum);
    scanoff_kernel<<<1, 64, 0, stream>>>(bsum, boff);
    rowstart_kernel<<<NSCAN, 256, 0, stream>>>(cnt, boff, row_start, cursor);
    scatter_kernel<<<1563, 256, 0, stream>>>(dst_idx, cursor, eorder);

    // mega-fused gather + LN
    fused_gather2<<<25000, 256, 0, stream>>>(
        row_start, eorder, src_idx, P_b, esf_b, v_b, aq, ak,
        Wcomb, cmv, W_merge, ln_gamma, ln_beta, (float*)d_out);
}

// Round 10
// 752.419 us; speedup vs baseline: 1.2627x; 1.0821x over previous
//
#include <hip/hip_runtime.h>
#include <math.h>
#include <stdio.h>
#include <stdint.h>

#define N_SRC 200000
#define N_DST 100000
#define NE    400000
// IN=128, H=8, D=32, H*D=256

#define SCAN_CHUNK 1024
#define NSCAN ((N_DST + SCAN_CHUNK - 1) / SCAN_CHUNK)   // 98

typedef short bf16x8 __attribute__((ext_vector_type(8)));
typedef float f32x4 __attribute__((ext_vector_type(4)));

__device__ __forceinline__ float bflo(unsigned int u) { return __uint_as_float(u << 16); }
__device__ __forceinline__ float bfhi(unsigned int u) { return __uint_as_float(u & 0xFFFF0000u); }
__device__ __forceinline__ unsigned short f2bf(float f) {
    unsigned int u = __float_as_uint(f);
    u += 0x7FFFu + ((u >> 16) & 1u);       // round-to-nearest-even
    return (unsigned short)(u >> 16);
}
// pack two f32 -> (bf16(f1)<<16)|bf16(f0) by truncation: single v_perm_b32
__device__ __forceinline__ unsigned int packbf(float f0, float f1) {
    return __builtin_amdgcn_perm(__float_as_uint(f1), __float_as_uint(f0), 0x07060302u);
}
// async global->LDS DMA, 16 bytes per lane (dest = wave-uniform base + lane*16)
__device__ __forceinline__ void gl2lds(const void* g, void* l) {
    __builtin_amdgcn_global_load_lds(
        (const __attribute__((address_space(1))) unsigned int*)g,
        (__attribute__((address_space(3))) unsigned int*)l, 16, 0, 0);
}

// ---------------------------------------------------------------------------
// m97-style GEMM: global_load_lds staging + counted-vmcnt double buffer.
// (unchanged from round 9 — GEMMs no longer dominate)
// ---------------------------------------------------------------------------
template<bool ABF, int K, int KP, int NT>
__global__ __launch_bounds__(256) void gemm_glds(
    const void* __restrict__ Ap, const unsigned short* __restrict__ Wf,
    const float* __restrict__ bias, const float* __restrict__ add_n,
    const float* __restrict__ add_c,
    unsigned short* __restrict__ out_lin, unsigned short* __restrict__ out_exp,
    int N, int C)
{
    constexpr int KST   = KP / 32;
    constexpr int ARB   = ABF ? 64 : 128;      // LDS A row bytes (32 elems)
    constexpr int ASTEP = 128 * ARB;           // 8KB (bf16) or 16KB (f32)
    __shared__ __align__(16) char As[2 * ASTEP];
    __shared__ __align__(16) char Bs[2 * 8192];

    const int tid  = threadIdx.x;
    const int lane = tid & 63;
    const int wv   = tid >> 6;
    const int fr   = lane & 15;
    const int fq   = lane >> 4;
    const int row0 = blockIdx.y * 128;
    const int nb0  = blockIdx.x * NT;
    const int NTC  = C / 16;

    f32x4 acc[2][NT];
#pragma unroll
    for (int m = 0; m < 2; ++m)
#pragma unroll
        for (int n = 0; n < NT; ++n) acc[m][n] = (f32x4){0.f, 0.f, 0.f, 0.f};

    auto stage = [&](int buf, int ks) {
        char* ab = As + buf * ASTEP;
        char* bb = Bs + buf * 8192;
        if (ABF) {
            const char* Ab = (const char*)Ap;
#pragma unroll
            for (int q = 0; q < 2; ++q) {
                int i   = wv * 2 + q;
                int row = i * 16 + (lane >> 2);
                int rr  = row0 + row; if (rr >= N) rr = N - 1;
                gl2lds(Ab + ((long)rr * K + ks * 32 + (lane & 3) * 8) * 2,
                       ab + i * 1024 + lane * 16);
            }
        } else {
            const char* Af = (const char*)Ap;
#pragma unroll
            for (int q = 0; q < 4; ++q) {
                int i   = wv * 4 + q;
                int row = i * 8 + (lane >> 3);
                int rr  = row0 + row; if (rr >= N) rr = N - 1;
                int kk  = ks * 32 + (lane & 7) * 4;
                long off = (long)rr * K + ((kk + 4 <= K) ? kk : 0);
                gl2lds(Af + off * 4, ab + i * 1024 + lane * 16);
            }
        }
        const char* wbase = (const char*)Wf + ((size_t)ks * NTC + nb0) * 1024;
#pragma unroll
        for (int q = 0; q < 2; ++q) {
            int i = wv * 2 + q;
            gl2lds(wbase + i * 1024 + lane * 16, bb + i * 1024 + lane * 16);
        }
    };

    stage(0, 0);
    for (int ks = 0; ks < KST; ++ks) {
        const int cur = ks & 1;
        if (ks + 1 < KST) {
            stage(cur ^ 1, ks + 1);
            if (ABF) asm volatile("s_waitcnt vmcnt(4)" ::: "memory");
            else     asm volatile("s_waitcnt vmcnt(6)" ::: "memory");
        } else {
            asm volatile("s_waitcnt vmcnt(0)" ::: "memory");
        }
        __builtin_amdgcn_s_barrier();

        const char* ab = As + cur * ASTEP;
        const char* bb = Bs + cur * 8192;
        bf16x8 a0, a1;
        if (ABF) {
            a0 = *(const bf16x8*)(ab + (wv * 32 +      fr) * 64 + fq * 16);
            a1 = *(const bf16x8*)(ab + (wv * 32 + 16 + fr) * 64 + fq * 16);
        } else {
            float4 f0 = *(const float4*)(ab + (wv * 32 +      fr) * 128 + fq * 32);
            float4 f1 = *(const float4*)(ab + (wv * 32 +      fr) * 128 + fq * 32 + 16);
            float4 f2 = *(const float4*)(ab + (wv * 32 + 16 + fr) * 128 + fq * 32);
            float4 f3 = *(const float4*)(ab + (wv * 32 + 16 + fr) * 128 + fq * 32 + 16);
            uint4 u0, u1;
            u0.x = packbf(f0.x, f0.y); u0.y = packbf(f0.z, f0.w);
            u0.z = packbf(f1.x, f1.y); u0.w = packbf(f1.z, f1.w);
            u1.x = packbf(f2.x, f2.y); u1.y = packbf(f2.z, f2.w);
            u1.z = packbf(f3.x, f3.y); u1.w = packbf(f3.z, f3.w);
            a0 = *(bf16x8*)&u0;
            a1 = *(bf16x8*)&u1;
        }
        uint4 pb[NT];
#pragma unroll
        for (int n = 0; n < NT; ++n)
            pb[n] = *(const uint4*)(bb + n * 1024 + lane * 16);
#pragma unroll
        for (int n = 0; n < NT; ++n) {
            acc[0][n] = __builtin_amdgcn_mfma_f32_16x16x32_bf16(a0, *(bf16x8*)&pb[n], acc[0][n], 0, 0, 0);
            acc[1][n] = __builtin_amdgcn_mfma_f32_16x16x32_bf16(a1, *(bf16x8*)&pb[n], acc[1][n], 0, 0, 0);
        }
        asm volatile("s_waitcnt lgkmcnt(0)" ::: "memory");
        __builtin_amdgcn_s_barrier();
    }

    // epilogue: D col = lane&15, row = (lane>>4)*4 + reg (measured m89/m91)
    float bc[NT];
#pragma unroll
    for (int n = 0; n < NT; ++n) {
        int col = (nb0 + n) * 16 + fr;
        float b = 0.f;
        if (bias)  b += bias[col];
        if (add_c) b += add_c[col];
        bc[n] = b;
    }
#pragma unroll
    for (int m = 0; m < 2; ++m) {
#pragma unroll
        for (int j = 0; j < 4; ++j) {
            int row = row0 + wv * 32 + m * 16 + fq * 4 + j;
            if (row >= N) continue;
#pragma unroll
            for (int n = 0; n < NT; ++n) {
                int col = (nb0 + n) * 16 + fr;
                float v = acc[m][n][j] + bc[n];
                if (add_n) v += add_n[(long)row * C + col];
                long o = (long)row * C + col;
                if (out_lin) out_lin[o] = f2bf(v);
                if (out_exp) out_exp[o] = f2bf(expf(v));
            }
        }
    }
}

// ---------------------------------------------------------------------------
// Weight f32 [C][K] -> bf16 B-fragment layout, [ks][n] major (padded K).
// ---------------------------------------------------------------------------
__global__ void wconv_frag(const float* __restrict__ src, unsigned short* __restrict__ dst,
                           int C, int K, int Kp)
{
    int NTC = C >> 4;
    int total = C * Kp;
    for (int i = blockIdx.x * blockDim.x + threadIdx.x; i < total; i += gridDim.x * blockDim.x) {
        int j  = i & 7;
        int l  = (i >> 3) & 63;
        int t  = i >> 9;
        int n  = t % NTC;
        int ks = t / NTC;
        int col = n * 16 + (l & 15);
        int k   = ks * 32 + ((l >> 4) << 3) + j;
        dst[i] = (k < K) ? f2bf(src[(long)col * K + k]) : (unsigned short)0;
    }
}

// ---------------------------------------------------------------------------
// Setup: fold W_na into Q/K, fold W_merge x W_eattn into Wcomb, cmv.
// ---------------------------------------------------------------------------
__global__ void eff_setup(const float* __restrict__ Wq, const float* __restrict__ bq,
                          const float* __restrict__ na_item,
                          const float* __restrict__ Wk, const float* __restrict__ bk,
                          const float* __restrict__ na_user,
                          const float* __restrict__ W_merge, const float* __restrict__ b_merge,
                          const float* __restrict__ W_eattn, const float* __restrict__ b_eattn,
                          float* __restrict__ wq_eff, float* __restrict__ bq_eff,
                          float* __restrict__ wk_eff, float* __restrict__ bk_eff,
                          float* __restrict__ Wcomb, float* __restrict__ cmv)
{
    int tid = threadIdx.x;
    for (int idx = tid; idx < 1024; idx += 256) {
        int h = idx >> 7, k = idx & 127;
        float s1 = 0.f, s2 = 0.f, s3 = 0.f;
        for (int d = 0; d < 32; ++d) {
            s1 += Wq[(h * 32 + d) * 128 + k] * na_item[d];
            s2 += Wk[(h * 32 + d) * 128 + k] * na_user[d];
        }
        for (int j = 0; j < 8; ++j)
            s3 += W_merge[h * 16 + 8 + j] * W_eattn[j * 128 + k];
        wq_eff[idx] = s1;
        wk_eff[idx] = s2;
        Wcomb[idx]  = s3;
    }
    if (tid < 8) {
        float s1 = 0.f, s2 = 0.f, s3 = b_merge[tid];
        for (int d = 0; d < 32; ++d) {
            s1 += bq[tid * 32 + d] * na_item[d];
            s2 += bk[tid * 32 + d] * na_user[d];
        }
        for (int j = 0; j < 8; ++j) s3 += W_merge[tid * 16 + 8 + j] * b_eattn[j];
        bq_eff[tid] = s1;
        bk_eff[tid] = s2;
        cmv[tid]    = s3;
    }
}

// ---------------------------------------------------------------------------
// Wave-per-row 8-head dot from bf16 features, transpose-butterfly reduce.
// ---------------------------------------------------------------------------
__global__ __launch_bounds__(256) void rowdot8_bf(
    const unsigned short* __restrict__ feat, const float* __restrict__ weff,
    const float* __restrict__ beff, float* __restrict__ out, int N)
{
    int gw   = (blockIdx.x * blockDim.x + threadIdx.x) >> 6;
    int lane = threadIdx.x & 63;
    if (gw >= N) return;
    int ch = lane * 2;
    unsigned int u = *(const unsigned int*)&feat[(long)gw * 128 + ch];
    float x0 = bflo(u), x1 = bfhi(u);
    float part[8];
#pragma unroll
    for (int h = 0; h < 8; ++h)
        part[h] = x0 * weff[h * 128 + ch] + x1 * weff[h * 128 + ch + 1];
    int b0 = lane & 1, b1 = (lane >> 1) & 1, b2 = (lane >> 2) & 1;
    float u0 = (b0 ? part[1] : part[0]) + __shfl_xor(b0 ? part[0] : part[1], 1);
    float u1 = (b0 ? part[3] : part[2]) + __shfl_xor(b0 ? part[2] : part[3], 1);
    float u2 = (b0 ? part[5] : part[4]) + __shfl_xor(b0 ? part[4] : part[5], 1);
    float u3 = (b0 ? part[7] : part[6]) + __shfl_xor(b0 ? part[6] : part[7], 1);
    float w0 = (b1 ? u1 : u0) + __shfl_xor(b1 ? u0 : u1, 2);
    float w1 = (b1 ? u3 : u2) + __shfl_xor(b1 ? u2 : u3, 2);
    float ts = (b2 ? w1 : w0) + __shfl_xor(b2 ? w0 : w1, 4);
    ts += __shfl_xor(ts, 8);
    ts += __shfl_xor(ts, 16);
    ts += __shfl_xor(ts, 32);
    if (lane < 8) out[(long)gw * 8 + lane] = ts + beff[lane];
}

// ---------------------------------------------------------------------------
// CSR build: histogram -> two-level scan -> scatter
// ---------------------------------------------------------------------------
__global__ void hist_kernel(const int* __restrict__ dst_idx, int* __restrict__ cnt)
{
    int e = blockIdx.x * blockDim.x + threadIdx.x;
    if (e < NE) atomicAdd(&cnt[dst_idx[e]], 1);
}

__global__ __launch_bounds__(256) void blocksum_kernel(const int* __restrict__ cnt,
                                                       int* __restrict__ bsum)
{
    __shared__ int sm[256];
    int b = blockIdx.x, t = threadIdx.x;
    int s = 0;
    for (int i = t; i < SCAN_CHUNK; i += 256) {
        int idx = b * SCAN_CHUNK + i;
        if (idx < N_DST) s += cnt[idx];
    }
    sm[t] = s; __syncthreads();
    for (int off = 128; off > 0; off >>= 1) {
        if (t < off) sm[t] += sm[t + off];
        __syncthreads();
    }
    if (t == 0) bsum[b] = sm[0];
}

__global__ void scanoff_kernel(const int* __restrict__ bsum, int* __restrict__ boff)
{
    if (threadIdx.x == 0) {
        int r = 0;
        for (int i = 0; i < NSCAN; ++i) { boff[i] = r; r += bsum[i]; }
    }
}

__global__ __launch_bounds__(256) void rowstart_kernel(
    const int* __restrict__ cnt, const int* __restrict__ boff,
    int* __restrict__ row_start, int* __restrict__ cursor)
{
    __shared__ int sm[256];
    int b = blockIdx.x, t = threadIdx.x;
    int base = b * SCAN_CHUNK + t * 4;
    int c[4]; int tot = 0;
#pragma unroll
    for (int j = 0; j < 4; ++j) {
        int idx = base + j;
        c[j] = (idx < N_DST) ? cnt[idx] : 0;
        tot += c[j];
    }
    sm[t] = tot; __syncthreads();
    for (int off = 1; off < 256; off <<= 1) {
        int v = (t >= off) ? sm[t - off] : 0;
        __syncthreads();
        sm[t] += v;
        __syncthreads();
    }
    int run = sm[t] - tot + boff[b];
#pragma unroll
    for (int j = 0; j < 4; ++j) {
        int idx = base + j;
        if (idx < N_DST) { row_start[idx] = run; cursor[idx] = run; run += c[j]; }
    }
    if (b == 0 && t == 0) row_start[N_DST] = NE;
}

__global__ void scatter_kernel(const int* __restrict__ dst_idx,
                               int* __restrict__ cursor, int* __restrict__ eorder)
{
    int e = blockIdx.x * blockDim.x + threadIdx.x;
    if (e >= NE) return;
    int pos = atomicAdd(&cursor[dst_idx[e]], 1);
    eorder[pos] = e;
}

// ---------------------------------------------------------------------------
// Mega-fused gather v3: batch-issued, register-cached edges (deg<=8 fast path).
// All index loads -> all src loads -> all {P,esf,ak,v} gathers issued as
// unrolled static register arrays (3 latency rounds instead of ~2*deg).
// pe/se/ex cached across both softmax passes (no pass-2 reloads).
// deg>8 falls back to the two-pass loop; deg==0 short-circuits to LN(0)=beta.
// ---------------------------------------------------------------------------
__global__ __launch_bounds__(256) void fused_gather3(
    const int* __restrict__ row_start, const int* __restrict__ eorder,
    const int* __restrict__ src_idx,
    const unsigned short* __restrict__ Pb, const unsigned short* __restrict__ esfb,
    const unsigned short* __restrict__ vb,
    const float* __restrict__ aq, const float* __restrict__ ak,
    const float* __restrict__ Wcomb, const float* __restrict__ cmv,
    const float* __restrict__ W_merge,
    const float* __restrict__ ln_gamma, const float* __restrict__ ln_beta,
    float* __restrict__ out)
{
    int gw   = (blockIdx.x * blockDim.x + threadIdx.x) >> 6;
    int lane = threadIdx.x & 63;
    if (gw >= N_DST) return;
    const int dst = gw;
    const int r0 = row_start[dst], r1 = row_start[dst + 1];
    const int deg = r1 - r0;
    const int ch = lane * 2;
    const int hl = lane & 7;
    const int g  = lane >> 3;
    const float rsc = 0.17677669529663687f;   // 1/sqrt(32)

    float ax = 0.f, ay = 0.f, az = 0.f, aw = 0.f;

    if (deg > 0) {
        float wc0[8], wc1[8];
#pragma unroll
        for (int h = 0; h < 8; ++h) {
            wc0[h] = Wcomb[h * 128 + ch];
            wc1[h] = Wcomb[h * 128 + ch + 1];
        }
        const float wself = W_merge[g * 16 + hl];
        const float cmg   = cmv[g];
        const float aqh   = aq[(long)dst * 8 + hl];

        if (deg <= 8) {
            // ---------------- fast path: batch-issued register cache ----------
            int eo[8], sr[8];
            unsigned int pe[8], se[8];
            float akv[8];
            uint2 vv[8];
#pragma unroll
            for (int j = 0; j < 8; ++j) { pe[j] = 0u; se[j] = 0u; akv[j] = 0.f;
                                          vv[j] = make_uint2(0u, 0u); }
            // level 1: edge ids (wave-uniform addresses -> broadcast loads)
#pragma unroll
            for (int j = 0; j < 8; ++j) if (j < deg) eo[j] = eorder[r0 + j];
            // level 2: src ids
#pragma unroll
            for (int j = 0; j < 8; ++j) if (j < deg) sr[j] = src_idx[eo[j]];
            // level 3: all gathers in flight together
#pragma unroll
            for (int j = 0; j < 8; ++j) if (j < deg) {
                pe[j]  = *(const unsigned int*)&Pb[(long)eo[j] * 128 + ch];
                se[j]  = *(const unsigned int*)&esfb[(long)sr[j] * 128 + ch];
                akv[j] = ak[(long)sr[j] * 8 + hl];
                vv[j]  = *(const uint2*)&vb[(long)sr[j] * 256 + lane * 4];
            }
            // pass 1: denominators (pure compute)
            float s1x = 0.f, s1y = 0.f, s2l = 0.f;
            float ex[8];
#pragma unroll
            for (int j = 0; j < 8; ++j) {
                s1x += bflo(pe[j]) * bflo(se[j]);
                s1y += bfhi(pe[j]) * bfhi(se[j]);
                float e = expf((akv[j] + aqh) * rsc);
                ex[j] = (j < deg) ? e : 0.f;
                s2l += ex[j];
            }
            const float i1x = 1.0f / s1x, i1y = 1.0f / s1y, i2 = 1.0f / s2l;
            // pass 2: attention + aggregate (no memory)
#pragma unroll
            for (int j = 0; j < 8; ++j) if (j < deg) {
                float t0 = bflo(pe[j]) * bflo(se[j]) * i1x;
                float t1 = bfhi(pe[j]) * bfhi(se[j]) * i1y;
                float part[8];
#pragma unroll
                for (int h = 0; h < 8; ++h) part[h] = t0 * wc0[h] + t1 * wc1[h];
                int b0 = lane & 1, b1 = (lane >> 1) & 1, b2 = (lane >> 2) & 1;
                float u0 = (b0 ? part[1] : part[0]) + __shfl_xor(b0 ? part[0] : part[1], 1);
                float u1 = (b0 ? part[3] : part[2]) + __shfl_xor(b0 ? part[2] : part[3], 1);
                float u2 = (b0 ? part[5] : part[4]) + __shfl_xor(b0 ? part[4] : part[5], 1);
                float u3 = (b0 ? part[7] : part[6]) + __shfl_xor(b0 ? part[6] : part[7], 1);
                float w0 = (b1 ? u1 : u0) + __shfl_xor(b1 ? u0 : u1, 2);
                float w1 = (b1 ? u3 : u2) + __shfl_xor(b1 ? u2 : u3, 2);
                float ts = (b2 ? w1 : w0) + __shfl_xor(b2 ? w0 : w1, 4);
                ts += __shfl_xor(ts, 8);
                ts += __shfl_xor(ts, 16);
                ts += __shfl_xor(ts, 32);
                float ms = wself * (ex[j] * i2);
                ms += __shfl_xor(ms, 1);
                ms += __shfl_xor(ms, 2);
                ms += __shfl_xor(ms, 4);
                float mm = cmg + ms + __shfl(ts, g);
                ax += mm * bflo(vv[j].x); ay += mm * bfhi(vv[j].x);
                az += mm * bflo(vv[j].y); aw += mm * bfhi(vv[j].y);
            }
        } else {
            // ---------------- slow path (deg > 8, ~2% of dsts) ----------------
            float s1x = 0.f, s1y = 0.f, s2l = 0.f;
            for (int j = r0; j < r1; ++j) {
                int eo  = eorder[j];
                int src = src_idx[eo];
                unsigned int pe = *(const unsigned int*)&Pb[(long)eo * 128 + ch];
                unsigned int se = *(const unsigned int*)&esfb[(long)src * 128 + ch];
                float akh = ak[(long)src * 8 + hl];
                s1x += bflo(pe) * bflo(se);
                s1y += bfhi(pe) * bfhi(se);
                s2l += expf((akh + aqh) * rsc);
            }
            const float i1x = 1.0f / s1x, i1y = 1.0f / s1y, i2 = 1.0f / s2l;
            for (int j = r0; j < r1; ++j) {
                int eo  = eorder[j];
                int src = src_idx[eo];
                unsigned int pe = *(const unsigned int*)&Pb[(long)eo * 128 + ch];
                unsigned int se = *(const unsigned int*)&esfb[(long)src * 128 + ch];
                float akh = ak[(long)src * 8 + hl];
                uint2 vv = *(const uint2*)&vb[(long)src * 256 + lane * 4];
                float t0 = bflo(pe) * bflo(se) * i1x;
                float t1 = bfhi(pe) * bfhi(se) * i1y;
                float part[8];
#pragma unroll
                for (int h = 0; h < 8; ++h) part[h] = t0 * wc0[h] + t1 * wc1[h];
                int b0 = lane & 1, b1 = (lane >> 1) & 1, b2 = (lane >> 2) & 1;
                float u0 = (b0 ? part[1] : part[0]) + __shfl_xor(b0 ? part[0] : part[1], 1);
                float u1 = (b0 ? part[3] : part[2]) + __shfl_xor(b0 ? part[2] : part[3], 1);
                float u2 = (b0 ? part[5] : part[4]) + __shfl_xor(b0 ? part[4] : part[5], 1);
                float u3 = (b0 ? part[7] : part[6]) + __shfl_xor(b0 ? part[6] : part[7], 1);
                float w0 = (b1 ? u1 : u0) + __shfl_xor(b1 ? u0 : u1, 2);
                float w1 = (b1 ? u3 : u2) + __shfl_xor(b1 ? u2 : u3, 2);
                float ts = (b2 ? w1 : w0) + __shfl_xor(b2 ? w0 : w1, 4);
                ts += __shfl_xor(ts, 8);
                ts += __shfl_xor(ts, 16);
                ts += __shfl_xor(ts, 32);
                float ms = wself * (expf((akh + aqh) * rsc) * i2);
                ms += __shfl_xor(ms, 1);
                ms += __shfl_xor(ms, 2);
                ms += __shfl_xor(ms, 4);
                float mm = cmg + ms + __shfl(ts, g);
                ax += mm * bflo(vv.x); ay += mm * bfhi(vv.x);
                az += mm * bflo(vv.y); aw += mm * bfhi(vv.y);
            }
        }
    }

    // ---- LayerNorm epilogue ----
    float s = ax + ay + az + aw;
    float q = ax * ax + ay * ay + az * az + aw * aw;
#pragma unroll
    for (int off = 32; off > 0; off >>= 1) {
        s += __shfl_xor(s, off);
        q += __shfl_xor(q, off);
    }
    float mu  = s * (1.0f / 256.0f);
    float var = q * (1.0f / 256.0f) - mu * mu;
    float inv = rsqrtf(var + 1e-5f);
    float4 gg = *(const float4*)&ln_gamma[lane * 4];
    float4 bb = *(const float4*)&ln_beta[lane * 4];
    float4 o;
    o.x = (ax - mu) * inv * gg.x + bb.x;
    o.y = (ay - mu) * inv * gg.y + bb.y;
    o.z = (az - mu) * inv * gg.z + bb.z;
    o.w = (aw - mu) * inv * gg.w + bb.w;
    *(float4*)&out[(long)dst * 256 + lane * 4] = o;
}

// ---------------------------------------------------------------------------
extern "C" void kernel_launch(void* const* d_in, const int* in_sizes, int n_in,
                              void* d_out, int out_size, void* d_ws, size_t ws_size,
                              hipStream_t stream)
{
    const float* x_user        = (const float*)d_in[0];
    const float* x_item        = (const float*)d_in[1];
    const float* node_emb_user = (const float*)d_in[2];
    const float* edge_emb      = (const float*)d_in[3];
    const float* edge_feats    = (const float*)d_in[4];
    const int*   src_idx       = (const int*)d_in[5];
    const int*   dst_idx       = (const int*)d_in[6];
    const float* W_nf_user     = (const float*)d_in[7];
    const float* b_nf_user     = (const float*)d_in[8];
    const float* W_nf_item     = (const float*)d_in[9];
    const float* b_nf_item     = (const float*)d_in[10];
    const float* W_ef          = (const float*)d_in[11];
    const float* b_ef          = (const float*)d_in[12];
    const float* W_eattn       = (const float*)d_in[13];
    const float* b_eattn       = (const float*)d_in[14];
    const float* W_merge       = (const float*)d_in[15];
    const float* b_merge       = (const float*)d_in[16];
    const float* W_q           = (const float*)d_in[17];
    const float* b_q           = (const float*)d_in[18];
    const float* W_k           = (const float*)d_in[19];
    const float* b_k           = (const float*)d_in[20];
    const float* W_v           = (const float*)d_in[21];
    const float* b_v           = (const float*)d_in[22];
    const float* W_na_user     = (const float*)d_in[23];
    const float* W_na_item     = (const float*)d_in[24];
    const float* ln_gamma      = (const float*)d_in[25];
    const float* ln_beta       = (const float*)d_in[26];

    unsigned short* us   = (unsigned short*)d_ws;
    unsigned short* sf_b  = us;                    // 25,600,000  bf16 src_feat
    unsigned short* esf_b = sf_b + 25600000;       // 25,600,000  bf16 exp(src_feat)
    unsigned short* dsf_b = esf_b + 25600000;      // 12,800,000  bf16 dst_feat
    unsigned short* P_b   = dsf_b + 12800000;      // 51,200,000  bf16 exp(ef)
    unsigned short* v_b   = P_b + 51200000;        // 51,200,000  bf16 v
    float* fz     = (float*)(v_b + 51200000);
    float* aq     = fz;                            // 800,000
    float* ak     = aq + 800000;                   // 1,600,000
    float* wq_eff = ak + 1600000;                  // 1024
    float* wk_eff = wq_eff + 1024;                 // 1024
    float* bq_eff = wk_eff + 1024;                 // 16
    float* bk_eff = bq_eff + 16;                   // 16
    float* Wcomb  = bk_eff + 16;                   // 1024
    float* cmv    = Wcomb + 1024;                  // 8
    int*   cnt       = (int*)(cmv + 8);            // N_DST
    int*   bsum      = cnt + N_DST;                // 128
    int*   boff      = bsum + 128;                 // 128
    int*   row_start = boff + 128;                 // N_DST + 1
    int*   cursor    = row_start + N_DST + 1;      // N_DST
    int*   eorder    = cursor + N_DST;             // NE
    // W fragment buffers (16B-aligned for gl_lds / dwordx4 loads)
    unsigned short* wub = (unsigned short*)(((uintptr_t)(eorder + NE) + 15) & ~(uintptr_t)15);
    unsigned short* wib = wub + 128 * 320;
    unsigned short* web = wib + 128 * 224;
    unsigned short* wvb = web + 128 * 64;
    size_t needed = (size_t)((char*)(wvb + 256 * 128) - (char*)d_ws);
    if (ws_size < needed) {
        fprintf(stderr, "kernel_launch: ws_size %zu < needed %zu\n", ws_size, needed);
        return;
    }

    hipMemsetAsync(cnt, 0, N_DST * sizeof(int), stream);

    eff_setup<<<1, 256, 0, stream>>>(W_q, b_q, W_na_item, W_k, b_k, W_na_user,
                                     W_merge, b_merge, W_eattn, b_eattn,
                                     wq_eff, bq_eff, wk_eff, bk_eff, Wcomb, cmv);

    // weight pre-conversion to bf16 B-fragment layout ([ks][n] major, padded K)
    wconv_frag<<<64, 256, 0, stream>>>(W_nf_user, wub, 128, 300, 320);
    wconv_frag<<<64, 256, 0, stream>>>(W_nf_item, wib, 128, 200, 224);
    wconv_frag<<<32, 256, 0, stream>>>(W_ef,      web, 128,  64,  64);
    wconv_frag<<<64, 256, 0, stream>>>(W_v,       wvb, 256, 128, 128);

    // GEMM1: src_feat = x_user@W_nf_user^T + b + node_emb + edge_emb -> sf_b & esf_b
    gemm_glds<false, 300, 320, 8><<<dim3(1, 1563), 256, 0, stream>>>(
        x_user, wub, b_nf_user, node_emb_user, edge_emb,
        sf_b, esf_b, N_SRC, 128);
    // GEMM2: dst_feat = x_item@W_nf_item^T + b + edge_emb -> dsf_b
    gemm_glds<false, 200, 224, 8><<<dim3(1, 782), 256, 0, stream>>>(
        x_item, wib, b_nf_item, nullptr, edge_emb,
        dsf_b, nullptr, N_DST, 128);
    // GEMM3: P = exp(edge_feats@W_ef^T + b_ef) -> P_b
    gemm_glds<false, 64, 64, 8><<<dim3(1, 3125), 256, 0, stream>>>(
        edge_feats, web, b_ef, nullptr, nullptr,
        nullptr, P_b, NE, 128);
    // GEMM4: v = sf@W_v^T + b_v -> v_b (A bf16; C=256 split over grid.x=2)
    gemm_glds<true, 128, 128, 8><<<dim3(2, 1563), 256, 0, stream>>>(
        sf_b, wvb, b_v, nullptr, nullptr,
        v_b, nullptr, N_SRC, 256);

    // aq / ak via folded weights
    rowdot8_bf<<<25000, 256, 0, stream>>>(dsf_b, wq_eff, bq_eff, aq, N_DST);
    rowdot8_bf<<<50000, 256, 0, stream>>>(sf_b, wk_eff, bk_eff, ak, N_SRC);

    // CSR build
    hist_kernel<<<1563, 256, 0, stream>>>(dst_idx, cnt);
    blocksum_kernel<<<NSCAN, 256, 0, stream>>>(cnt, bsum);
    scanoff_kernel<<<1, 64, 0, stream>>>(bsum, boff);
    rowstart_kernel<<<NSCAN, 256, 0, stream>>>(cnt, boff, row_start, cursor);
    scatter_kernel<<<1563, 256, 0, stream>>>(dst_idx, cursor, eorder);

    // mega-fused gather + LN
    fused_gather3<<<25000, 256, 0, stream>>>(
        row_start, eorder, src_idx, P_b, esf_b, v_b, aq, ak,
        Wcomb, cmv, W_merge, ln_gamma, ln_beta, (float*)d_out);
}

// Round 11
// 657.120 us; speedup vs baseline: 1.4459x; 1.1450x over previous
//
#include <hip/hip_runtime.h>
#include <math.h>
#include <stdio.h>
#include <stdint.h>

#define N_SRC 200000
#define N_DST 100000
#define NE    400000
// IN=128, H=8, D=32, H*D=256

#define SCAN_CHUNK 1024
#define NSCAN ((N_DST + SCAN_CHUNK - 1) / SCAN_CHUNK)   // 98

typedef short bf16x8 __attribute__((ext_vector_type(8)));
typedef float f32x4 __attribute__((ext_vector_type(4)));

__device__ __forceinline__ float bflo(unsigned int u) { return __uint_as_float(u << 16); }
__device__ __forceinline__ float bfhi(unsigned int u) { return __uint_as_float(u & 0xFFFF0000u); }
__device__ __forceinline__ unsigned short f2bf(float f) {
    unsigned int u = __float_as_uint(f);
    u += 0x7FFFu + ((u >> 16) & 1u);       // round-to-nearest-even
    return (unsigned short)(u >> 16);
}
__device__ __forceinline__ unsigned int packbf(float f0, float f1) {
    return __builtin_amdgcn_perm(__float_as_uint(f1), __float_as_uint(f0), 0x07060302u);
}
// async global->LDS DMA, 16 bytes per lane (dest = wave-uniform base + lane*16)
__device__ __forceinline__ void gl2lds(const void* g, void* l) {
    __builtin_amdgcn_global_load_lds(
        (const __attribute__((address_space(1))) unsigned int*)g,
        (__attribute__((address_space(3))) unsigned int*)l, 16, 0, 0);
}

// ---------------------------------------------------------------------------
// Fused producer GEMM (gl_lds staging, counted vmcnt, source-swizzled A).
// main:  acc = A(f32)[128 rows] @ W^T (+bias+add_c+add_n); optional bf16/exp
//        global outputs; sf rows also written bf16 to LDS tile T (swizzled).
// FUSEV: v = sf @ Wv^T + b_v  (2 col-halves x 4 K-steps, B-frags from L2)
// DOT:   dotout[r][h<8] = sf[r] . wdot[h]  (one zero-padded 16-col B-frag)
// Swizzle (rule 21): LDS dest linear (gl_lds), global SOURCE chunk-XORed,
// reads XOR back -> A-frag ds_read 2-lane/bank (free). K-tail junk lands at
// logical k>=K and is annihilated by zero-padded B fragments.
// ---------------------------------------------------------------------------
template<int K, int KP, int NT, bool FUSEV, bool DOT>
__global__ __launch_bounds__(256) void gemm_fused(
    const float* __restrict__ Ap, const unsigned short* __restrict__ Wf,
    const float* __restrict__ bias, const float* __restrict__ add_n,
    const float* __restrict__ add_c,
    unsigned short* __restrict__ out_lin, unsigned short* __restrict__ out_exp,
    const unsigned short* __restrict__ wvfrag, const float* __restrict__ bv,
    unsigned short* __restrict__ vout,
    const unsigned short* __restrict__ dotfrag, float* __restrict__ dotout,
    int N, int C)
{
    constexpr int KST = KP / 32;
    __shared__ __align__(16) char LDSB[49152];
    char* As = LDSB;            // 2 x 16384 (f32 A step)
    char* Bs = LDSB + 32768;    // 2 x 8192
    char* T  = LDSB;            // 128 x 256B bf16 sf tile (reused after main)

    const int tid  = threadIdx.x;
    const int lane = tid & 63;
    const int wv   = tid >> 6;
    const int fr   = lane & 15;
    const int fq   = lane >> 4;
    const int row0 = blockIdx.y * 128;
    const int NTC  = C / 16;

    f32x4 acc[2][NT];
#pragma unroll
    for (int m = 0; m < 2; ++m)
#pragma unroll
        for (int n = 0; n < NT; ++n) acc[m][n] = (f32x4){0.f, 0.f, 0.f, 0.f};

    const int csw = (lane & 7) ^ (lane >> 3);   // source-swizzled chunk (A stage)

    auto stage = [&](int buf, int ks) {
        char* ab = As + buf * 16384;
        char* bb = Bs + buf * 8192;
        const char* Af = (const char*)Ap;
#pragma unroll
        for (int q = 0; q < 4; ++q) {
            int i   = wv * 4 + q;
            int row = i * 8 + (lane >> 3);
            int rr  = row0 + row; if (rr >= N) rr = N - 1;
            int kk  = ks * 32 + csw * 4;
            long off = (long)rr * K + ((kk + 4 <= K) ? kk : 0);
            gl2lds(Af + off * 4, ab + i * 1024 + lane * 16);
        }
        const char* wbase = (const char*)Wf + ((size_t)ks * NTC) * 1024;
#pragma unroll
        for (int q = 0; q < 2; ++q) {
            int i = wv * 2 + q;
            gl2lds(wbase + i * 1024 + lane * 16, bb + i * 1024 + lane * 16);
        }
    };

    stage(0, 0);
    for (int ks = 0; ks < KST; ++ks) {
        const int cur = ks & 1;
        if (ks + 1 < KST) {
            stage(cur ^ 1, ks + 1);
            asm volatile("s_waitcnt vmcnt(6)" ::: "memory");
        } else {
            asm volatile("s_waitcnt vmcnt(0)" ::: "memory");
        }
        __builtin_amdgcn_s_barrier();

        const char* ab = As + cur * 16384;
        const char* bb = Bs + cur * 8192;
        // swizzled A-frag reads: logical chunk c at physical (c ^ (r&7))
        const int rA = fr & 7;
        float4 f0 = *(const float4*)(ab + (wv * 32 +      fr) * 128 + ((2 * fq)     ^ rA) * 16);
        float4 f1 = *(const float4*)(ab + (wv * 32 +      fr) * 128 + ((2 * fq + 1) ^ rA) * 16);
        float4 f2 = *(const float4*)(ab + (wv * 32 + 16 + fr) * 128 + ((2 * fq)     ^ rA) * 16);
        float4 f3 = *(const float4*)(ab + (wv * 32 + 16 + fr) * 128 + ((2 * fq + 1) ^ rA) * 16);
        uint4 u0, u1;
        u0.x = packbf(f0.x, f0.y); u0.y = packbf(f0.z, f0.w);
        u0.z = packbf(f1.x, f1.y); u0.w = packbf(f1.z, f1.w);
        u1.x = packbf(f2.x, f2.y); u1.y = packbf(f2.z, f2.w);
        u1.z = packbf(f3.x, f3.y); u1.w = packbf(f3.z, f3.w);
        bf16x8 a0 = *(bf16x8*)&u0;
        bf16x8 a1 = *(bf16x8*)&u1;
        uint4 pb[NT];
#pragma unroll
        for (int n = 0; n < NT; ++n)
            pb[n] = *(const uint4*)(bb + n * 1024 + lane * 16);
#pragma unroll
        for (int n = 0; n < NT; ++n) {
            acc[0][n] = __builtin_amdgcn_mfma_f32_16x16x32_bf16(a0, *(bf16x8*)&pb[n], acc[0][n], 0, 0, 0);
            acc[1][n] = __builtin_amdgcn_mfma_f32_16x16x32_bf16(a1, *(bf16x8*)&pb[n], acc[1][n], 0, 0, 0);
        }
        asm volatile("s_waitcnt lgkmcnt(0)" ::: "memory");
        __builtin_amdgcn_s_barrier();
    }

    // ---- main epilogue: D col = lane&15, row = (lane>>4)*4 + reg (m89/m91) ----
    float bc[NT];
#pragma unroll
    for (int n = 0; n < NT; ++n) {
        int col = n * 16 + fr;
        float b = 0.f;
        if (bias)  b += bias[col];
        if (add_c) b += add_c[col];
        bc[n] = b;
    }
#pragma unroll
    for (int m = 0; m < 2; ++m) {
#pragma unroll
        for (int j = 0; j < 4; ++j) {
            int rl  = wv * 32 + m * 16 + fq * 4 + j;   // local row
            int row = row0 + rl;
            bool rok = (row < N);
#pragma unroll
            for (int n = 0; n < NT; ++n) {
                int col = n * 16 + fr;
                float v = acc[m][n][j] + bc[n];
                if (add_n && rok) v += add_n[(long)row * C + col];
                unsigned short bf = f2bf(v);
                if (FUSEV || DOT) {
                    int c = col >> 3;
                    *(unsigned short*)(T + rl * 256 + ((c ^ (rl & 7)) * 16) + (col & 7) * 2) = bf;
                }
                if (rok) {
                    long o = (long)row * C + col;
                    if (out_lin) out_lin[o] = bf;
                    if (out_exp) out_exp[o] = f2bf(expf(v));
                }
            }
        }
    }

    if (FUSEV || DOT) {
        __syncthreads();    // T fully written
        // swizzled T fragment: row r, logical chunk c (16B) at c ^ (r&7)
        auto tfrag = [&](int r, int c) -> bf16x8 {
            return *(const bf16x8*)(T + r * 256 + ((c ^ (r & 7)) * 16));
        };
        if (DOT) {
            f32x4 da[2];
            da[0] = (f32x4){0.f, 0.f, 0.f, 0.f};
            da[1] = (f32x4){0.f, 0.f, 0.f, 0.f};
#pragma unroll
            for (int ks = 0; ks < 4; ++ks) {
                bf16x8 bf = *(const bf16x8*)&dotfrag[((size_t)ks * 64 + lane) * 8];
                bf16x8 t0 = tfrag(wv * 32 +      fr, ks * 4 + fq);
                bf16x8 t1 = tfrag(wv * 32 + 16 + fr, ks * 4 + fq);
                da[0] = __builtin_amdgcn_mfma_f32_16x16x32_bf16(t0, bf, da[0], 0, 0, 0);
                da[1] = __builtin_amdgcn_mfma_f32_16x16x32_bf16(t1, bf, da[1], 0, 0, 0);
            }
#pragma unroll
            for (int m = 0; m < 2; ++m)
#pragma unroll
                for (int j = 0; j < 4; ++j) {
                    int row = row0 + wv * 32 + m * 16 + fq * 4 + j;
                    if (fr < 8 && row < N) dotout[(long)row * 8 + fr] = da[m][j];
                }
        }
        if (FUSEV) {
#pragma unroll
            for (int half = 0; half < 2; ++half) {
                f32x4 va[2][8];
#pragma unroll
                for (int m = 0; m < 2; ++m)
#pragma unroll
                    for (int n = 0; n < 8; ++n) va[m][n] = (f32x4){0.f, 0.f, 0.f, 0.f};
#pragma unroll
                for (int ks = 0; ks < 4; ++ks) {
                    bf16x8 t0 = tfrag(wv * 32 +      fr, ks * 4 + fq);
                    bf16x8 t1 = tfrag(wv * 32 + 16 + fr, ks * 4 + fq);
                    uint4 vb4[8];
#pragma unroll
                    for (int n = 0; n < 8; ++n)
                        vb4[n] = *(const uint4*)&wvfrag[(((size_t)ks * 16 + half * 8 + n) * 64 + lane) * 8];
#pragma unroll
                    for (int n = 0; n < 8; ++n) {
                        va[0][n] = __builtin_amdgcn_mfma_f32_16x16x32_bf16(t0, *(bf16x8*)&vb4[n], va[0][n], 0, 0, 0);
                        va[1][n] = __builtin_amdgcn_mfma_f32_16x16x32_bf16(t1, *(bf16x8*)&vb4[n], va[1][n], 0, 0, 0);
                    }
                }
#pragma unroll
                for (int m = 0; m < 2; ++m)
#pragma unroll
                    for (int j = 0; j < 4; ++j) {
                        int row = row0 + wv * 32 + m * 16 + fq * 4 + j;
                        if (row >= N) continue;
#pragma unroll
                        for (int n = 0; n < 8; ++n) {
                            int col = half * 128 + n * 16 + fr;
                            vout[(long)row * 256 + col] = f2bf(va[m][n][j] + bv[col]);
                        }
                    }
            }
        }
    }
}

// ---------------------------------------------------------------------------
// Weight f32 [C][K] -> bf16 B-fragment layout, [ks][n] major (padded K).
// ---------------------------------------------------------------------------
__global__ void wconv_frag(const float* __restrict__ src, unsigned short* __restrict__ dst,
                           int C, int K, int Kp)
{
    int NTC = C >> 4;
    int total = C * Kp;
    for (int i = blockIdx.x * blockDim.x + threadIdx.x; i < total; i += gridDim.x * blockDim.x) {
        int j  = i & 7;
        int l  = (i >> 3) & 63;
        int t  = i >> 9;
        int n  = t % NTC;
        int ks = t / NTC;
        int col = n * 16 + (l & 15);
        int k   = ks * 32 + ((l >> 4) << 3) + j;
        dst[i] = (k < K) ? f2bf(src[(long)col * K + k]) : (unsigned short)0;
    }
}

// ---------------------------------------------------------------------------
// Setup: fold W_na into Q/K, fold W_merge x W_eattn into Wcomb, cmv; ALSO
// emit wq/wk as zero-padded 16-col bf16 B-fragments ([4ks][64][8]).
// ---------------------------------------------------------------------------
__global__ void eff_setup(const float* __restrict__ Wq, const float* __restrict__ bq,
                          const float* __restrict__ na_item,
                          const float* __restrict__ Wk, const float* __restrict__ bk,
                          const float* __restrict__ na_user,
                          const float* __restrict__ W_merge, const float* __restrict__ b_merge,
                          const float* __restrict__ W_eattn, const float* __restrict__ b_eattn,
                          float* __restrict__ wq_eff, float* __restrict__ bq_eff,
                          float* __restrict__ wk_eff, float* __restrict__ bk_eff,
                          float* __restrict__ Wcomb, float* __restrict__ cmv,
                          unsigned short* __restrict__ wqf, unsigned short* __restrict__ wkf)
{
    int tid = threadIdx.x;
    for (int idx = tid; idx < 1024; idx += 256) {
        int h = idx >> 7, k = idx & 127;
        float s1 = 0.f, s2 = 0.f, s3 = 0.f;
        for (int d = 0; d < 32; ++d) {
            s1 += Wq[(h * 32 + d) * 128 + k] * na_item[d];
            s2 += Wk[(h * 32 + d) * 128 + k] * na_user[d];
        }
        for (int j = 0; j < 8; ++j)
            s3 += W_merge[h * 16 + 8 + j] * W_eattn[j * 128 + k];
        wq_eff[idx] = s1;
        wk_eff[idx] = s2;
        Wcomb[idx]  = s3;
    }
    if (tid < 8) {
        float s1 = 0.f, s2 = 0.f, s3 = b_merge[tid];
        for (int d = 0; d < 32; ++d) {
            s1 += bq[tid * 32 + d] * na_item[d];
            s2 += bk[tid * 32 + d] * na_user[d];
        }
        for (int j = 0; j < 8; ++j) s3 += W_merge[tid * 16 + 8 + j] * b_eattn[j];
        bq_eff[tid] = s1;
        bk_eff[tid] = s2;
        cmv[tid]    = s3;
    }
    __syncthreads();
    // fragment build: dst[(ks*64+l)*8+j] = W[col= l&15][k = ks*32 + (l>>4)*8 + j]
    for (int idx = tid; idx < 2048; idx += 256) {
        int j  = idx & 7;
        int l  = (idx >> 3) & 63;
        int ks = idx >> 9;
        int col = l & 15;
        int k   = ks * 32 + ((l >> 4) << 3) + j;
        wqf[idx] = (col < 8) ? f2bf(wq_eff[col * 128 + k]) : (unsigned short)0;
        wkf[idx] = (col < 8) ? f2bf(wk_eff[col * 128 + k]) : (unsigned short)0;
    }
}

// ---------------------------------------------------------------------------
// CSR build: histogram -> two-level scan -> scatter
// ---------------------------------------------------------------------------
__global__ void hist_kernel(const int* __restrict__ dst_idx, int* __restrict__ cnt)
{
    int e = blockIdx.x * blockDim.x + threadIdx.x;
    if (e < NE) atomicAdd(&cnt[dst_idx[e]], 1);
}

__global__ __launch_bounds__(256) void blocksum_kernel(const int* __restrict__ cnt,
                                                       int* __restrict__ bsum)
{
    __shared__ int sm[256];
    int b = blockIdx.x, t = threadIdx.x;
    int s = 0;
    for (int i = t; i < SCAN_CHUNK; i += 256) {
        int idx = b * SCAN_CHUNK + i;
        if (idx < N_DST) s += cnt[idx];
    }
    sm[t] = s; __syncthreads();
    for (int off = 128; off > 0; off >>= 1) {
        if (t < off) sm[t] += sm[t + off];
        __syncthreads();
    }
    if (t == 0) bsum[b] = sm[0];
}

__global__ void scanoff_kernel(const int* __restrict__ bsum, int* __restrict__ boff)
{
    if (threadIdx.x == 0) {
        int r = 0;
        for (int i = 0; i < NSCAN; ++i) { boff[i] = r; r += bsum[i]; }
    }
}

__global__ __launch_bounds__(256) void rowstart_kernel(
    const int* __restrict__ cnt, const int* __restrict__ boff,
    int* __restrict__ row_start, int* __restrict__ cursor)
{
    __shared__ int sm[256];
    int b = blockIdx.x, t = threadIdx.x;
    int base = b * SCAN_CHUNK + t * 4;
    int c[4]; int tot = 0;
#pragma unroll
    for (int j = 0; j < 4; ++j) {
        int idx = base + j;
        c[j] = (idx < N_DST) ? cnt[idx] : 0;
        tot += c[j];
    }
    sm[t] = tot; __syncthreads();
    for (int off = 1; off < 256; off <<= 1) {
        int v = (t >= off) ? sm[t - off] : 0;
        __syncthreads();
        sm[t] += v;
        __syncthreads();
    }
    int run = sm[t] - tot + boff[b];
#pragma unroll
    for (int j = 0; j < 4; ++j) {
        int idx = base + j;
        if (idx < N_DST) { row_start[idx] = run; cursor[idx] = run; run += c[j]; }
    }
    if (b == 0 && t == 0) row_start[N_DST] = NE;
}

__global__ void scatter_kernel(const int* __restrict__ dst_idx,
                               int* __restrict__ cursor, int* __restrict__ eorder)
{
    int e = blockIdx.x * blockDim.x + threadIdx.x;
    if (e >= NE) return;
    int pos = atomicAdd(&cursor[dst_idx[e]], 1);
    eorder[pos] = e;
}

// ---------------------------------------------------------------------------
// Mega-fused gather v3 (unchanged from round 10).
// ---------------------------------------------------------------------------
__global__ __launch_bounds__(256) void fused_gather3(
    const int* __restrict__ row_start, const int* __restrict__ eorder,
    const int* __restrict__ src_idx,
    const unsigned short* __restrict__ Pb, const unsigned short* __restrict__ esfb,
    const unsigned short* __restrict__ vb,
    const float* __restrict__ aq, const float* __restrict__ ak,
    const float* __restrict__ Wcomb, const float* __restrict__ cmv,
    const float* __restrict__ W_merge,
    const float* __restrict__ ln_gamma, const float* __restrict__ ln_beta,
    float* __restrict__ out)
{
    int gw   = (blockIdx.x * blockDim.x + threadIdx.x) >> 6;
    int lane = threadIdx.x & 63;
    if (gw >= N_DST) return;
    const int dst = gw;
    const int r0 = row_start[dst], r1 = row_start[dst + 1];
    const int deg = r1 - r0;
    const int ch = lane * 2;
    const int hl = lane & 7;
    const int g  = lane >> 3;
    const float rsc = 0.17677669529663687f;   // 1/sqrt(32)

    float ax = 0.f, ay = 0.f, az = 0.f, aw = 0.f;

    if (deg > 0) {
        float wc0[8], wc1[8];
#pragma unroll
        for (int h = 0; h < 8; ++h) {
            wc0[h] = Wcomb[h * 128 + ch];
            wc1[h] = Wcomb[h * 128 + ch + 1];
        }
        const float wself = W_merge[g * 16 + hl];
        const float cmg   = cmv[g];
        const float aqh   = aq[(long)dst * 8 + hl];

        if (deg <= 8) {
            int eo[8], sr[8];
            unsigned int pe[8], se[8];
            float akv[8];
            uint2 vv[8];
#pragma unroll
            for (int j = 0; j < 8; ++j) { pe[j] = 0u; se[j] = 0u; akv[j] = 0.f;
                                          vv[j] = make_uint2(0u, 0u); }
#pragma unroll
            for (int j = 0; j < 8; ++j) if (j < deg) eo[j] = eorder[r0 + j];
#pragma unroll
            for (int j = 0; j < 8; ++j) if (j < deg) sr[j] = src_idx[eo[j]];
#pragma unroll
            for (int j = 0; j < 8; ++j) if (j < deg) {
                pe[j]  = *(const unsigned int*)&Pb[(long)eo[j] * 128 + ch];
                se[j]  = *(const unsigned int*)&esfb[(long)sr[j] * 128 + ch];
                akv[j] = ak[(long)sr[j] * 8 + hl];
                vv[j]  = *(const uint2*)&vb[(long)sr[j] * 256 + lane * 4];
            }
            float s1x = 0.f, s1y = 0.f, s2l = 0.f;
            float ex[8];
#pragma unroll
            for (int j = 0; j < 8; ++j) {
                s1x += bflo(pe[j]) * bflo(se[j]);
                s1y += bfhi(pe[j]) * bfhi(se[j]);
                float e = expf((akv[j] + aqh) * rsc);
                ex[j] = (j < deg) ? e : 0.f;
                s2l += ex[j];
            }
            const float i1x = 1.0f / s1x, i1y = 1.0f / s1y, i2 = 1.0f / s2l;
#pragma unroll
            for (int j = 0; j < 8; ++j) if (j < deg) {
                float t0 = bflo(pe[j]) * bflo(se[j]) * i1x;
                float t1 = bfhi(pe[j]) * bfhi(se[j]) * i1y;
                float part[8];
#pragma unroll
                for (int h = 0; h < 8; ++h) part[h] = t0 * wc0[h] + t1 * wc1[h];
                int b0 = lane & 1, b1 = (lane >> 1) & 1, b2 = (lane >> 2) & 1;
                float u0 = (b0 ? part[1] : part[0]) + __shfl_xor(b0 ? part[0] : part[1], 1);
                float u1 = (b0 ? part[3] : part[2]) + __shfl_xor(b0 ? part[2] : part[3], 1);
                float u2 = (b0 ? part[5] : part[4]) + __shfl_xor(b0 ? part[4] : part[5], 1);
                float u3 = (b0 ? part[7] : part[6]) + __shfl_xor(b0 ? part[6] : part[7], 1);
                float w0 = (b1 ? u1 : u0) + __shfl_xor(b1 ? u0 : u1, 2);
                float w1 = (b1 ? u3 : u2) + __shfl_xor(b1 ? u2 : u3, 2);
                float ts = (b2 ? w1 : w0) + __shfl_xor(b2 ? w0 : w1, 4);
                ts += __shfl_xor(ts, 8);
                ts += __shfl_xor(ts, 16);
                ts += __shfl_xor(ts, 32);
                float ms = wself * (ex[j] * i2);
                ms += __shfl_xor(ms, 1);
                ms += __shfl_xor(ms, 2);
                ms += __shfl_xor(ms, 4);
                float mm = cmg + ms + __shfl(ts, g);
                ax += mm * bflo(vv[j].x); ay += mm * bfhi(vv[j].x);
                az += mm * bflo(vv[j].y); aw += mm * bfhi(vv[j].y);
            }
        } else {
            float s1x = 0.f, s1y = 0.f, s2l = 0.f;
            for (int j = r0; j < r1; ++j) {
                int eo  = eorder[j];
                int src = src_idx[eo];
                unsigned int pe = *(const unsigned int*)&Pb[(long)eo * 128 + ch];
                unsigned int se = *(const unsigned int*)&esfb[(long)src * 128 + ch];
                float akh = ak[(long)src * 8 + hl];
                s1x += bflo(pe) * bflo(se);
                s1y += bfhi(pe) * bfhi(se);
                s2l += expf((akh + aqh) * rsc);
            }
            const float i1x = 1.0f / s1x, i1y = 1.0f / s1y, i2 = 1.0f / s2l;
            for (int j = r0; j < r1; ++j) {
                int eo  = eorder[j];
                int src = src_idx[eo];
                unsigned int pe = *(const unsigned int*)&Pb[(long)eo * 128 + ch];
                unsigned int se = *(const unsigned int*)&esfb[(long)src * 128 + ch];
                float akh = ak[(long)src * 8 + hl];
                uint2 vv = *(const uint2*)&vb[(long)src * 256 + lane * 4];
                float t0 = bflo(pe) * bflo(se) * i1x;
                float t1 = bfhi(pe) * bfhi(se) * i1y;
                float part[8];
#pragma unroll
                for (int h = 0; h < 8; ++h) part[h] = t0 * wc0[h] + t1 * wc1[h];
                int b0 = lane & 1, b1 = (lane >> 1) & 1, b2 = (lane >> 2) & 1;
                float u0 = (b0 ? part[1] : part[0]) + __shfl_xor(b0 ? part[0] : part[1], 1);
                float u1 = (b0 ? part[3] : part[2]) + __shfl_xor(b0 ? part[2] : part[3], 1);
                float u2 = (b0 ? part[5] : part[4]) + __shfl_xor(b0 ? part[4] : part[5], 1);
                float u3 = (b0 ? part[7] : part[6]) + __shfl_xor(b0 ? part[6] : part[7], 1);
                float w0 = (b1 ? u1 : u0) + __shfl_xor(b1 ? u0 : u1, 2);
                float w1 = (b1 ? u3 : u2) + __shfl_xor(b1 ? u2 : u3, 2);
                float ts = (b2 ? w1 : w0) + __shfl_xor(b2 ? w0 : w1, 4);
                ts += __shfl_xor(ts, 8);
                ts += __shfl_xor(ts, 16);
                ts += __shfl_xor(ts, 32);
                float ms = wself * (expf((akh + aqh) * rsc) * i2);
                ms += __shfl_xor(ms, 1);
                ms += __shfl_xor(ms, 2);
                ms += __shfl_xor(ms, 4);
                float mm = cmg + ms + __shfl(ts, g);
                ax += mm * bflo(vv.x); ay += mm * bfhi(vv.x);
                az += mm * bflo(vv.y); aw += mm * bfhi(vv.y);
            }
        }
    }

    float s = ax + ay + az + aw;
    float q = ax * ax + ay * ay + az * az + aw * aw;
#pragma unroll
    for (int off = 32; off > 0; off >>= 1) {
        s += __shfl_xor(s, off);
        q += __shfl_xor(q, off);
    }
    float mu  = s * (1.0f / 256.0f);
    float var = q * (1.0f / 256.0f) - mu * mu;
    float inv = rsqrtf(var + 1e-5f);
    float4 gg = *(const float4*)&ln_gamma[lane * 4];
    float4 bb = *(const float4*)&ln_beta[lane * 4];
    float4 o;
    o.x = (ax - mu) * inv * gg.x + bb.x;
    o.y = (ay - mu) * inv * gg.y + bb.y;
    o.z = (az - mu) * inv * gg.z + bb.z;
    o.w = (aw - mu) * inv * gg.w + bb.w;
    *(float4*)&out[(long)dst * 256 + lane * 4] = o;
}

// ---------------------------------------------------------------------------
extern "C" void kernel_launch(void* const* d_in, const int* in_sizes, int n_in,
                              void* d_out, int out_size, void* d_ws, size_t ws_size,
                              hipStream_t stream)
{
    const float* x_user        = (const float*)d_in[0];
    const float* x_item        = (const float*)d_in[1];
    const float* node_emb_user = (const float*)d_in[2];
    const float* edge_emb      = (const float*)d_in[3];
    const float* edge_feats    = (const float*)d_in[4];
    const int*   src_idx       = (const int*)d_in[5];
    const int*   dst_idx       = (const int*)d_in[6];
    const float* W_nf_user     = (const float*)d_in[7];
    const float* b_nf_user     = (const float*)d_in[8];
    const float* W_nf_item     = (const float*)d_in[9];
    const float* b_nf_item     = (const float*)d_in[10];
    const float* W_ef          = (const float*)d_in[11];
    const float* b_ef          = (const float*)d_in[12];
    const float* W_eattn       = (const float*)d_in[13];
    const float* b_eattn       = (const float*)d_in[14];
    const float* W_merge       = (const float*)d_in[15];
    const float* b_merge       = (const float*)d_in[16];
    const float* W_q           = (const float*)d_in[17];
    const float* b_q           = (const float*)d_in[18];
    const float* W_k           = (const float*)d_in[19];
    const float* b_k           = (const float*)d_in[20];
    const float* W_v           = (const float*)d_in[21];
    const float* b_v           = (const float*)d_in[22];
    const float* W_na_user     = (const float*)d_in[23];
    const float* W_na_item     = (const float*)d_in[24];
    const float* ln_gamma      = (const float*)d_in[25];
    const float* ln_beta       = (const float*)d_in[26];

    unsigned short* us    = (unsigned short*)d_ws;
    unsigned short* esf_b = us;                    // 25,600,000  bf16 exp(src_feat)
    unsigned short* P_b   = esf_b + 25600000;      // 51,200,000  bf16 exp(ef)
    unsigned short* v_b   = P_b + 51200000;        // 51,200,000  bf16 v
    float* fz     = (float*)(v_b + 51200000);
    float* aq     = fz;                            // 800,000
    float* ak     = aq + 800000;                   // 1,600,000
    float* wq_eff = ak + 1600000;                  // 1024
    float* wk_eff = wq_eff + 1024;                 // 1024
    float* bq_eff = wk_eff + 1024;                 // 16
    float* bk_eff = bq_eff + 16;                   // 16
    float* Wcomb  = bk_eff + 16;                   // 1024
    float* cmv    = Wcomb + 1024;                  // 8
    int*   cnt       = (int*)(cmv + 8);            // N_DST
    int*   bsum      = cnt + N_DST;                // 128
    int*   boff      = bsum + 128;                 // 128
    int*   row_start = boff + 128;                 // N_DST + 1
    int*   cursor    = row_start + N_DST + 1;      // N_DST
    int*   eorder    = cursor + N_DST;             // NE
    unsigned short* wub = (unsigned short*)(((uintptr_t)(eorder + NE) + 15) & ~(uintptr_t)15);
    unsigned short* wib = wub + 128 * 320;
    unsigned short* web = wib + 128 * 224;
    unsigned short* wvb = web + 128 * 64;          // 256*128
    unsigned short* wqf = wvb + 256 * 128;         // 2048
    unsigned short* wkf = wqf + 2048;              // 2048
    size_t needed = (size_t)((char*)(wkf + 2048) - (char*)d_ws);
    if (ws_size < needed) {
        fprintf(stderr, "kernel_launch: ws_size %zu < needed %zu\n", ws_size, needed);
        return;
    }

    hipMemsetAsync(cnt, 0, N_DST * sizeof(int), stream);

    eff_setup<<<1, 256, 0, stream>>>(W_q, b_q, W_na_item, W_k, b_k, W_na_user,
                                     W_merge, b_merge, W_eattn, b_eattn,
                                     wq_eff, bq_eff, wk_eff, bk_eff, Wcomb, cmv,
                                     wqf, wkf);

    wconv_frag<<<64, 256, 0, stream>>>(W_nf_user, wub, 128, 300, 320);
    wconv_frag<<<64, 256, 0, stream>>>(W_nf_item, wib, 128, 200, 224);
    wconv_frag<<<32, 256, 0, stream>>>(W_ef,      web, 128,  64,  64);
    wconv_frag<<<64, 256, 0, stream>>>(W_v,       wvb, 256, 128, 128);

    // GEMM1 fused: src_feat -> esf_b (exp only), v_b (FUSEV), ak (DOT)
    gemm_fused<300, 320, 8, true, true><<<dim3(1, 1563), 256, 0, stream>>>(
        x_user, wub, b_nf_user, node_emb_user, edge_emb,
        nullptr, esf_b, wvb, b_v, v_b, wkf, ak, N_SRC, 128);
    // GEMM2 fused: dst_feat -> aq only (no global feature output needed)
    gemm_fused<200, 224, 8, false, true><<<dim3(1, 782), 256, 0, stream>>>(
        x_item, wib, b_nf_item, nullptr, edge_emb,
        nullptr, nullptr, nullptr, nullptr, nullptr, wqf, aq, N_DST, 128);
    // GEMM3: P = exp(edge_feats@W_ef^T + b_ef) -> P_b
    gemm_fused<64, 64, 8, false, false><<<dim3(1, 3125), 256, 0, stream>>>(
        edge_feats, web, b_ef, nullptr, nullptr,
        nullptr, P_b, nullptr, nullptr, nullptr, nullptr, nullptr, NE, 128);

    // CSR build
    hist_kernel<<<1563, 256, 0, stream>>>(dst_idx, cnt);
    blocksum_kernel<<<NSCAN, 256, 0, stream>>>(cnt, bsum);
    scanoff_kernel<<<1, 64, 0, stream>>>(bsum, boff);
    rowstart_kernel<<<NSCAN, 256, 0, stream>>>(cnt, boff, row_start, cursor);
    scatter_kernel<<<1563, 256, 0, stream>>>(dst_idx, cursor, eorder);

    // mega-fused gather + LN
    fused_gather3<<<25000, 256, 0, stream>>>(
        row_start, eorder, src_idx, P_b, esf_b, v_b, aq, ak,
        Wcomb, cmv, W_merge, ln_gamma, ln_beta, (float*)d_out);
}

// Round 12
// 652.275 us; speedup vs baseline: 1.4566x; 1.0074x over previous
//
#include <hip/hip_runtime.h>
#include <hip/hip_fp16.h>
#include <math.h>
#include <stdio.h>
#include <stdint.h>

#define N_SRC 200000
#define N_DST 100000
#define NE    400000
// IN=128, H=8, D=32, H*D=256

#define SCAN_CHUNK 1024
#define NSCAN ((N_DST + SCAN_CHUNK - 1) / SCAN_CHUNK)   // 98

typedef short bf16x8 __attribute__((ext_vector_type(8)));
typedef float f32x4 __attribute__((ext_vector_type(4)));

__device__ __forceinline__ float bflo(unsigned int u) { return __uint_as_float(u << 16); }
__device__ __forceinline__ float bfhi(unsigned int u) { return __uint_as_float(u & 0xFFFF0000u); }
__device__ __forceinline__ unsigned short f2bf(float f) {
    unsigned int u = __float_as_uint(f);
    u += 0x7FFFu + ((u >> 16) & 1u);       // round-to-nearest-even
    return (unsigned short)(u >> 16);
}
__device__ __forceinline__ unsigned int packbf(float f0, float f1) {
    return __builtin_amdgcn_perm(__float_as_uint(f1), __float_as_uint(f0), 0x07060302u);
}
// f32 -> fp8 e5m2 (via f16 RNE, then RNE to top 8 bits). exp() outputs are >0,
// <= ~3e3 << 57344 (e5m2 max): no overflow path.
__device__ __forceinline__ unsigned char f2e5(float f) {
    __half h = __float2half(f);
    unsigned short b = *reinterpret_cast<unsigned short*>(&h);
    b = (unsigned short)(b + 0x7Fu + ((b >> 8) & 1u));
    return (unsigned char)(b >> 8);
}
// fp8 e5m2 -> f32 (reinterpret as f16 upper byte; handles subnormals)
__device__ __forceinline__ float e52f(unsigned int b8) {
    unsigned short h = (unsigned short)(b8 << 8);
    __half hh = *reinterpret_cast<__half*>(&h);
    return __half2float(hh);
}
// async global->LDS DMA, 16 bytes per lane
__device__ __forceinline__ void gl2lds(const void* g, void* l) {
    __builtin_amdgcn_global_load_lds(
        (const __attribute__((address_space(1))) unsigned int*)g,
        (__attribute__((address_space(3))) unsigned int*)l, 16, 0, 0);
}

// ---------------------------------------------------------------------------
// Fused producer GEMM (gl_lds staging, counted vmcnt, source-swizzled A).
// out_lin: bf16 linear output; out_exp: fp8-e5m2 exp(output).
// FUSEV: v = sf@Wv^T + b_v from LDS sf tile; DOT: 8-head row dot (zero-pad frag).
// ---------------------------------------------------------------------------
template<int K, int KP, int NT, bool FUSEV, bool DOT>
__global__ __launch_bounds__(256) void gemm_fused(
    const float* __restrict__ Ap, const unsigned short* __restrict__ Wf,
    const float* __restrict__ bias, const float* __restrict__ add_n,
    const float* __restrict__ add_c,
    unsigned short* __restrict__ out_lin, unsigned char* __restrict__ out_exp,
    const unsigned short* __restrict__ wvfrag, const float* __restrict__ bv,
    unsigned short* __restrict__ vout,
    const unsigned short* __restrict__ dotfrag, float* __restrict__ dotout,
    int N, int C)
{
    constexpr int KST = KP / 32;
    __shared__ __align__(16) char LDSB[49152];
    char* As = LDSB;            // 2 x 16384 (f32 A step)
    char* Bs = LDSB + 32768;    // 2 x 8192
    char* T  = LDSB;            // 128 x 256B bf16 sf tile (reused after main)

    const int tid  = threadIdx.x;
    const int lane = tid & 63;
    const int wv   = tid >> 6;
    const int fr   = lane & 15;
    const int fq   = lane >> 4;
    const int row0 = blockIdx.y * 128;
    const int NTC  = C / 16;

    f32x4 acc[2][NT];
#pragma unroll
    for (int m = 0; m < 2; ++m)
#pragma unroll
        for (int n = 0; n < NT; ++n) acc[m][n] = (f32x4){0.f, 0.f, 0.f, 0.f};

    const int csw = (lane & 7) ^ (lane >> 3);   // source-swizzled chunk (A stage)

    auto stage = [&](int buf, int ks) {
        char* ab = As + buf * 16384;
        char* bb = Bs + buf * 8192;
        const char* Af = (const char*)Ap;
#pragma unroll
        for (int q = 0; q < 4; ++q) {
            int i   = wv * 4 + q;
            int row = i * 8 + (lane >> 3);
            int rr  = row0 + row; if (rr >= N) rr = N - 1;
            int kk  = ks * 32 + csw * 4;
            long off = (long)rr * K + ((kk + 4 <= K) ? kk : 0);
            gl2lds(Af + off * 4, ab + i * 1024 + lane * 16);
        }
        const char* wbase = (const char*)Wf + ((size_t)ks * NTC) * 1024;
#pragma unroll
        for (int q = 0; q < 2; ++q) {
            int i = wv * 2 + q;
            gl2lds(wbase + i * 1024 + lane * 16, bb + i * 1024 + lane * 16);
        }
    };

    stage(0, 0);
    for (int ks = 0; ks < KST; ++ks) {
        const int cur = ks & 1;
        if (ks + 1 < KST) {
            stage(cur ^ 1, ks + 1);
            asm volatile("s_waitcnt vmcnt(6)" ::: "memory");
        } else {
            asm volatile("s_waitcnt vmcnt(0)" ::: "memory");
        }
        __builtin_amdgcn_s_barrier();

        const char* ab = As + cur * 16384;
        const char* bb = Bs + cur * 8192;
        const int rA = fr & 7;
        float4 f0 = *(const float4*)(ab + (wv * 32 +      fr) * 128 + ((2 * fq)     ^ rA) * 16);
        float4 f1 = *(const float4*)(ab + (wv * 32 +      fr) * 128 + ((2 * fq + 1) ^ rA) * 16);
        float4 f2 = *(const float4*)(ab + (wv * 32 + 16 + fr) * 128 + ((2 * fq)     ^ rA) * 16);
        float4 f3 = *(const float4*)(ab + (wv * 32 + 16 + fr) * 128 + ((2 * fq + 1) ^ rA) * 16);
        uint4 u0, u1;
        u0.x = packbf(f0.x, f0.y); u0.y = packbf(f0.z, f0.w);
        u0.z = packbf(f1.x, f1.y); u0.w = packbf(f1.z, f1.w);
        u1.x = packbf(f2.x, f2.y); u1.y = packbf(f2.z, f2.w);
        u1.z = packbf(f3.x, f3.y); u1.w = packbf(f3.z, f3.w);
        bf16x8 a0 = *(bf16x8*)&u0;
        bf16x8 a1 = *(bf16x8*)&u1;
        uint4 pb[NT];
#pragma unroll
        for (int n = 0; n < NT; ++n)
            pb[n] = *(const uint4*)(bb + n * 1024 + lane * 16);
#pragma unroll
        for (int n = 0; n < NT; ++n) {
            acc[0][n] = __builtin_amdgcn_mfma_f32_16x16x32_bf16(a0, *(bf16x8*)&pb[n], acc[0][n], 0, 0, 0);
            acc[1][n] = __builtin_amdgcn_mfma_f32_16x16x32_bf16(a1, *(bf16x8*)&pb[n], acc[1][n], 0, 0, 0);
        }
        asm volatile("s_waitcnt lgkmcnt(0)" ::: "memory");
        __builtin_amdgcn_s_barrier();
    }

    // ---- main epilogue: D col = lane&15, row = (lane>>4)*4 + reg (m89/m91) ----
    float bc[NT];
#pragma unroll
    for (int n = 0; n < NT; ++n) {
        int col = n * 16 + fr;
        float b = 0.f;
        if (bias)  b += bias[col];
        if (add_c) b += add_c[col];
        bc[n] = b;
    }
#pragma unroll
    for (int m = 0; m < 2; ++m) {
#pragma unroll
        for (int j = 0; j < 4; ++j) {
            int rl  = wv * 32 + m * 16 + fq * 4 + j;   // local row
            int row = row0 + rl;
            bool rok = (row < N);
#pragma unroll
            for (int n = 0; n < NT; ++n) {
                int col = n * 16 + fr;
                float v = acc[m][n][j] + bc[n];
                if (add_n && rok) v += add_n[(long)row * C + col];
                unsigned short bf = f2bf(v);
                if (FUSEV || DOT) {
                    int c = col >> 3;
                    *(unsigned short*)(T + rl * 256 + ((c ^ (rl & 7)) * 16) + (col & 7) * 2) = bf;
                }
                if (rok) {
                    long o = (long)row * C + col;
                    if (out_lin) out_lin[o] = bf;
                    if (out_exp) out_exp[o] = f2e5(expf(v));
                }
            }
        }
    }

    if (FUSEV || DOT) {
        __syncthreads();    // T fully written
        auto tfrag = [&](int r, int c) -> bf16x8 {
            return *(const bf16x8*)(T + r * 256 + ((c ^ (r & 7)) * 16));
        };
        if (DOT) {
            f32x4 da[2];
            da[0] = (f32x4){0.f, 0.f, 0.f, 0.f};
            da[1] = (f32x4){0.f, 0.f, 0.f, 0.f};
#pragma unroll
            for (int ks = 0; ks < 4; ++ks) {
                bf16x8 bf = *(const bf16x8*)&dotfrag[((size_t)ks * 64 + lane) * 8];
                bf16x8 t0 = tfrag(wv * 32 +      fr, ks * 4 + fq);
                bf16x8 t1 = tfrag(wv * 32 + 16 + fr, ks * 4 + fq);
                da[0] = __builtin_amdgcn_mfma_f32_16x16x32_bf16(t0, bf, da[0], 0, 0, 0);
                da[1] = __builtin_amdgcn_mfma_f32_16x16x32_bf16(t1, bf, da[1], 0, 0, 0);
            }
#pragma unroll
            for (int m = 0; m < 2; ++m)
#pragma unroll
                for (int j = 0; j < 4; ++j) {
                    int row = row0 + wv * 32 + m * 16 + fq * 4 + j;
                    if (fr < 8 && row < N) dotout[(long)row * 8 + fr] = da[m][j];
                }
        }
        if (FUSEV) {
#pragma unroll
            for (int half = 0; half < 2; ++half) {
                f32x4 va[2][8];
#pragma unroll
                for (int m = 0; m < 2; ++m)
#pragma unroll
                    for (int n = 0; n < 8; ++n) va[m][n] = (f32x4){0.f, 0.f, 0.f, 0.f};
#pragma unroll
                for (int ks = 0; ks < 4; ++ks) {
                    bf16x8 t0 = tfrag(wv * 32 +      fr, ks * 4 + fq);
                    bf16x8 t1 = tfrag(wv * 32 + 16 + fr, ks * 4 + fq);
                    uint4 vb4[8];
#pragma unroll
                    for (int n = 0; n < 8; ++n)
                        vb4[n] = *(const uint4*)&wvfrag[(((size_t)ks * 16 + half * 8 + n) * 64 + lane) * 8];
#pragma unroll
                    for (int n = 0; n < 8; ++n) {
                        va[0][n] = __builtin_amdgcn_mfma_f32_16x16x32_bf16(t0, *(bf16x8*)&vb4[n], va[0][n], 0, 0, 0);
                        va[1][n] = __builtin_amdgcn_mfma_f32_16x16x32_bf16(t1, *(bf16x8*)&vb4[n], va[1][n], 0, 0, 0);
                    }
                }
#pragma unroll
                for (int m = 0; m < 2; ++m)
#pragma unroll
                    for (int j = 0; j < 4; ++j) {
                        int row = row0 + wv * 32 + m * 16 + fq * 4 + j;
                        if (row >= N) continue;
#pragma unroll
                        for (int n = 0; n < 8; ++n) {
                            int col = half * 128 + n * 16 + fr;
                            vout[(long)row * 256 + col] = f2bf(va[m][n][j] + bv[col]);
                        }
                    }
            }
        }
    }
}

// ---------------------------------------------------------------------------
// Weight f32 [C][K] -> bf16 B-fragment layout, [ks][n] major (padded K).
// ---------------------------------------------------------------------------
__global__ void wconv_frag(const float* __restrict__ src, unsigned short* __restrict__ dst,
                           int C, int K, int Kp)
{
    int NTC = C >> 4;
    int total = C * Kp;
    for (int i = blockIdx.x * blockDim.x + threadIdx.x; i < total; i += gridDim.x * blockDim.x) {
        int j  = i & 7;
        int l  = (i >> 3) & 63;
        int t  = i >> 9;
        int n  = t % NTC;
        int ks = t / NTC;
        int col = n * 16 + (l & 15);
        int k   = ks * 32 + ((l >> 4) << 3) + j;
        dst[i] = (k < K) ? f2bf(src[(long)col * K + k]) : (unsigned short)0;
    }
}

// ---------------------------------------------------------------------------
// Setup: folded weights + wq/wk zero-padded 16-col bf16 B-fragments.
// ---------------------------------------------------------------------------
__global__ void eff_setup(const float* __restrict__ Wq, const float* __restrict__ bq,
                          const float* __restrict__ na_item,
                          const float* __restrict__ Wk, const float* __restrict__ bk,
                          const float* __restrict__ na_user,
                          const float* __restrict__ W_merge, const float* __restrict__ b_merge,
                          const float* __restrict__ W_eattn, const float* __restrict__ b_eattn,
                          float* __restrict__ wq_eff, float* __restrict__ bq_eff,
                          float* __restrict__ wk_eff, float* __restrict__ bk_eff,
                          float* __restrict__ Wcomb, float* __restrict__ cmv,
                          unsigned short* __restrict__ wqf, unsigned short* __restrict__ wkf)
{
    int tid = threadIdx.x;
    for (int idx = tid; idx < 1024; idx += 256) {
        int h = idx >> 7, k = idx & 127;
        float s1 = 0.f, s2 = 0.f, s3 = 0.f;
        for (int d = 0; d < 32; ++d) {
            s1 += Wq[(h * 32 + d) * 128 + k] * na_item[d];
            s2 += Wk[(h * 32 + d) * 128 + k] * na_user[d];
        }
        for (int j = 0; j < 8; ++j)
            s3 += W_merge[h * 16 + 8 + j] * W_eattn[j * 128 + k];
        wq_eff[idx] = s1;
        wk_eff[idx] = s2;
        Wcomb[idx]  = s3;
    }
    if (tid < 8) {
        float s1 = 0.f, s2 = 0.f, s3 = b_merge[tid];
        for (int d = 0; d < 32; ++d) {
            s1 += bq[tid * 32 + d] * na_item[d];
            s2 += bk[tid * 32 + d] * na_user[d];
        }
        for (int j = 0; j < 8; ++j) s3 += W_merge[tid * 16 + 8 + j] * b_eattn[j];
        bq_eff[tid] = s1;
        bk_eff[tid] = s2;
        cmv[tid]    = s3;
    }
    __syncthreads();
    for (int idx = tid; idx < 2048; idx += 256) {
        int j  = idx & 7;
        int l  = (idx >> 3) & 63;
        int ks = idx >> 9;
        int col = l & 15;
        int k   = ks * 32 + ((l >> 4) << 3) + j;
        wqf[idx] = (col < 8) ? f2bf(wq_eff[col * 128 + k]) : (unsigned short)0;
        wkf[idx] = (col < 8) ? f2bf(wk_eff[col * 128 + k]) : (unsigned short)0;
    }
}

// ---------------------------------------------------------------------------
// CSR build: histogram -> two-level scan -> scatter
// ---------------------------------------------------------------------------
__global__ void hist_kernel(const int* __restrict__ dst_idx, int* __restrict__ cnt)
{
    int e = blockIdx.x * blockDim.x + threadIdx.x;
    if (e < NE) atomicAdd(&cnt[dst_idx[e]], 1);
}

__global__ __launch_bounds__(256) void blocksum_kernel(const int* __restrict__ cnt,
                                                       int* __restrict__ bsum)
{
    __shared__ int sm[256];
    int b = blockIdx.x, t = threadIdx.x;
    int s = 0;
    for (int i = t; i < SCAN_CHUNK; i += 256) {
        int idx = b * SCAN_CHUNK + i;
        if (idx < N_DST) s += cnt[idx];
    }
    sm[t] = s; __syncthreads();
    for (int off = 128; off > 0; off >>= 1) {
        if (t < off) sm[t] += sm[t + off];
        __syncthreads();
    }
    if (t == 0) bsum[b] = sm[0];
}

__global__ void scanoff_kernel(const int* __restrict__ bsum, int* __restrict__ boff)
{
    if (threadIdx.x == 0) {
        int r = 0;
        for (int i = 0; i < NSCAN; ++i) { boff[i] = r; r += bsum[i]; }
    }
}

__global__ __launch_bounds__(256) void rowstart_kernel(
    const int* __restrict__ cnt, const int* __restrict__ boff,
    int* __restrict__ row_start, int* __restrict__ cursor)
{
    __shared__ int sm[256];
    int b = blockIdx.x, t = threadIdx.x;
    int base = b * SCAN_CHUNK + t * 4;
    int c[4]; int tot = 0;
#pragma unroll
    for (int j = 0; j < 4; ++j) {
        int idx = base + j;
        c[j] = (idx < N_DST) ? cnt[idx] : 0;
        tot += c[j];
    }
    sm[t] = tot; __syncthreads();
    for (int off = 1; off < 256; off <<= 1) {
        int v = (t >= off) ? sm[t - off] : 0;
        __syncthreads();
        sm[t] += v;
        __syncthreads();
    }
    int run = sm[t] - tot + boff[b];
#pragma unroll
    for (int j = 0; j < 4; ++j) {
        int idx = base + j;
        if (idx < N_DST) { row_start[idx] = run; cursor[idx] = run; run += c[j]; }
    }
    if (b == 0 && t == 0) row_start[N_DST] = NE;
}

__global__ void scatter_kernel(const int* __restrict__ dst_idx,
                               int* __restrict__ cursor, int* __restrict__ eorder)
{
    int e = blockIdx.x * blockDim.x + threadIdx.x;
    if (e >= NE) return;
    int pos = atomicAdd(&cursor[dst_idx[e]], 1);
    eorder[pos] = e;
}

// ---------------------------------------------------------------------------
// Mega-fused gather v4: batch-issued register cache + fp8 P/esf decode.
// ---------------------------------------------------------------------------
__global__ __launch_bounds__(256) void fused_gather4(
    const int* __restrict__ row_start, const int* __restrict__ eorder,
    const int* __restrict__ src_idx,
    const unsigned char* __restrict__ Pb, const unsigned char* __restrict__ esfb,
    const unsigned short* __restrict__ vb,
    const float* __restrict__ aq, const float* __restrict__ ak,
    const float* __restrict__ Wcomb, const float* __restrict__ cmv,
    const float* __restrict__ W_merge,
    const float* __restrict__ ln_gamma, const float* __restrict__ ln_beta,
    float* __restrict__ out)
{
    int gw   = (blockIdx.x * blockDim.x + threadIdx.x) >> 6;
    int lane = threadIdx.x & 63;
    if (gw >= N_DST) return;
    const int dst = gw;
    const int r0 = row_start[dst], r1 = row_start[dst + 1];
    const int deg = r1 - r0;
    const int ch = lane * 2;
    const int hl = lane & 7;
    const int g  = lane >> 3;
    const float rsc = 0.17677669529663687f;   // 1/sqrt(32)

    float ax = 0.f, ay = 0.f, az = 0.f, aw = 0.f;

    if (deg > 0) {
        float wc0[8], wc1[8];
#pragma unroll
        for (int h = 0; h < 8; ++h) {
            wc0[h] = Wcomb[h * 128 + ch];
            wc1[h] = Wcomb[h * 128 + ch + 1];
        }
        const float wself = W_merge[g * 16 + hl];
        const float cmg   = cmv[g];
        const float aqh   = aq[(long)dst * 8 + hl];

        if (deg <= 8) {
            int eo[8], sr[8];
            unsigned int pu[8], su[8];
            float akv[8];
            uint2 vv[8];
#pragma unroll
            for (int j = 0; j < 8; ++j) { pu[j] = 0u; su[j] = 0u; akv[j] = 0.f;
                                          vv[j] = make_uint2(0u, 0u); }
#pragma unroll
            for (int j = 0; j < 8; ++j) if (j < deg) eo[j] = eorder[r0 + j];
#pragma unroll
            for (int j = 0; j < 8; ++j) if (j < deg) sr[j] = src_idx[eo[j]];
#pragma unroll
            for (int j = 0; j < 8; ++j) if (j < deg) {
                pu[j]  = *(const unsigned short*)&Pb[(long)eo[j] * 128 + ch];
                su[j]  = *(const unsigned short*)&esfb[(long)sr[j] * 128 + ch];
                akv[j] = ak[(long)sr[j] * 8 + hl];
                vv[j]  = *(const uint2*)&vb[(long)sr[j] * 256 + lane * 4];
            }
            // decode + pass 1 denominators
            float z0[8], z1[8], ex[8];
            float s1x = 0.f, s1y = 0.f, s2l = 0.f;
#pragma unroll
            for (int j = 0; j < 8; ++j) {
                z0[j] = e52f(pu[j] & 0xFFu) * e52f(su[j] & 0xFFu);
                z1[j] = e52f(pu[j] >> 8)    * e52f(su[j] >> 8);
                s1x += z0[j];
                s1y += z1[j];
                float e = expf((akv[j] + aqh) * rsc);
                ex[j] = (j < deg) ? e : 0.f;
                s2l += ex[j];
            }
            const float i1x = 1.0f / fmaxf(s1x, 1e-35f);
            const float i1y = 1.0f / fmaxf(s1y, 1e-35f);
            const float i2  = 1.0f / s2l;
#pragma unroll
            for (int j = 0; j < 8; ++j) if (j < deg) {
                float t0 = z0[j] * i1x;
                float t1 = z1[j] * i1y;
                float part[8];
#pragma unroll
                for (int h = 0; h < 8; ++h) part[h] = t0 * wc0[h] + t1 * wc1[h];
                int b0 = lane & 1, b1 = (lane >> 1) & 1, b2 = (lane >> 2) & 1;
                float u0 = (b0 ? part[1] : part[0]) + __shfl_xor(b0 ? part[0] : part[1], 1);
                float u1 = (b0 ? part[3] : part[2]) + __shfl_xor(b0 ? part[2] : part[3], 1);
                float u2 = (b0 ? part[5] : part[4]) + __shfl_xor(b0 ? part[4] : part[5], 1);
                float u3 = (b0 ? part[7] : part[6]) + __shfl_xor(b0 ? part[6] : part[7], 1);
                float w0 = (b1 ? u1 : u0) + __shfl_xor(b1 ? u0 : u1, 2);
                float w1 = (b1 ? u3 : u2) + __shfl_xor(b1 ? u2 : u3, 2);
                float ts = (b2 ? w1 : w0) + __shfl_xor(b2 ? w0 : w1, 4);
                ts += __shfl_xor(ts, 8);
                ts += __shfl_xor(ts, 16);
                ts += __shfl_xor(ts, 32);
                float ms = wself * (ex[j] * i2);
                ms += __shfl_xor(ms, 1);
                ms += __shfl_xor(ms, 2);
                ms += __shfl_xor(ms, 4);
                float mm = cmg + ms + __shfl(ts, g);
                ax += mm * bflo(vv[j].x); ay += mm * bfhi(vv[j].x);
                az += mm * bflo(vv[j].y); aw += mm * bfhi(vv[j].y);
            }
        } else {
            float s1x = 0.f, s1y = 0.f, s2l = 0.f;
            for (int j = r0; j < r1; ++j) {
                int eo  = eorder[j];
                int src = src_idx[eo];
                unsigned int pu = *(const unsigned short*)&Pb[(long)eo * 128 + ch];
                unsigned int su = *(const unsigned short*)&esfb[(long)src * 128 + ch];
                float akh = ak[(long)src * 8 + hl];
                s1x += e52f(pu & 0xFFu) * e52f(su & 0xFFu);
                s1y += e52f(pu >> 8)    * e52f(su >> 8);
                s2l += expf((akh + aqh) * rsc);
            }
            const float i1x = 1.0f / fmaxf(s1x, 1e-35f);
            const float i1y = 1.0f / fmaxf(s1y, 1e-35f);
            const float i2  = 1.0f / s2l;
            for (int j = r0; j < r1; ++j) {
                int eo  = eorder[j];
                int src = src_idx[eo];
                unsigned int pu = *(const unsigned short*)&Pb[(long)eo * 128 + ch];
                unsigned int su = *(const unsigned short*)&esfb[(long)src * 128 + ch];
                float akh = ak[(long)src * 8 + hl];
                uint2 vv = *(const uint2*)&vb[(long)src * 256 + lane * 4];
                float t0 = e52f(pu & 0xFFu) * e52f(su & 0xFFu) * i1x;
                float t1 = e52f(pu >> 8)    * e52f(su >> 8)    * i1y;
                float part[8];
#pragma unroll
                for (int h = 0; h < 8; ++h) part[h] = t0 * wc0[h] + t1 * wc1[h];
                int b0 = lane & 1, b1 = (lane >> 1) & 1, b2 = (lane >> 2) & 1;
                float u0 = (b0 ? part[1] : part[0]) + __shfl_xor(b0 ? part[0] : part[1], 1);
                float u1 = (b0 ? part[3] : part[2]) + __shfl_xor(b0 ? part[2] : part[3], 1);
                float u2 = (b0 ? part[5] : part[4]) + __shfl_xor(b0 ? part[4] : part[5], 1);
                float u3 = (b0 ? part[7] : part[6]) + __shfl_xor(b0 ? part[6] : part[7], 1);
                float w0 = (b1 ? u1 : u0) + __shfl_xor(b1 ? u0 : u1, 2);
                float w1 = (b1 ? u3 : u2) + __shfl_xor(b1 ? u2 : u3, 2);
                float ts = (b2 ? w1 : w0) + __shfl_xor(b2 ? w0 : w1, 4);
                ts += __shfl_xor(ts, 8);
                ts += __shfl_xor(ts, 16);
                ts += __shfl_xor(ts, 32);
                float ms = wself * (expf((akh + aqh) * rsc) * i2);
                ms += __shfl_xor(ms, 1);
                ms += __shfl_xor(ms, 2);
                ms += __shfl_xor(ms, 4);
                float mm = cmg + ms + __shfl(ts, g);
                ax += mm * bflo(vv.x); ay += mm * bfhi(vv.x);
                az += mm * bflo(vv.y); aw += mm * bfhi(vv.y);
            }
        }
    }

    float s = ax + ay + az + aw;
    float q = ax * ax + ay * ay + az * az + aw * aw;
#pragma unroll
    for (int off = 32; off > 0; off >>= 1) {
        s += __shfl_xor(s, off);
        q += __shfl_xor(q, off);
    }
    float mu  = s * (1.0f / 256.0f);
    float var = q * (1.0f / 256.0f) - mu * mu;
    float inv = rsqrtf(var + 1e-5f);
    float4 gg = *(const float4*)&ln_gamma[lane * 4];
    float4 bb = *(const float4*)&ln_beta[lane * 4];
    float4 o;
    o.x = (ax - mu) * inv * gg.x + bb.x;
    o.y = (ay - mu) * inv * gg.y + bb.y;
    o.z = (az - mu) * inv * gg.z + bb.z;
    o.w = (aw - mu) * inv * gg.w + bb.w;
    *(float4*)&out[(long)dst * 256 + lane * 4] = o;
}

// ---------------------------------------------------------------------------
extern "C" void kernel_launch(void* const* d_in, const int* in_sizes, int n_in,
                              void* d_out, int out_size, void* d_ws, size_t ws_size,
                              hipStream_t stream)
{
    const float* x_user        = (const float*)d_in[0];
    const float* x_item        = (const float*)d_in[1];
    const float* node_emb_user = (const float*)d_in[2];
    const float* edge_emb      = (const float*)d_in[3];
    const float* edge_feats    = (const float*)d_in[4];
    const int*   src_idx       = (const int*)d_in[5];
    const int*   dst_idx       = (const int*)d_in[6];
    const float* W_nf_user     = (const float*)d_in[7];
    const float* b_nf_user     = (const float*)d_in[8];
    const float* W_nf_item     = (const float*)d_in[9];
    const float* b_nf_item     = (const float*)d_in[10];
    const float* W_ef          = (const float*)d_in[11];
    const float* b_ef          = (const float*)d_in[12];
    const float* W_eattn       = (const float*)d_in[13];
    const float* b_eattn       = (const float*)d_in[14];
    const float* W_merge       = (const float*)d_in[15];
    const float* b_merge       = (const float*)d_in[16];
    const float* W_q           = (const float*)d_in[17];
    const float* b_q           = (const float*)d_in[18];
    const float* W_k           = (const float*)d_in[19];
    const float* b_k           = (const float*)d_in[20];
    const float* W_v           = (const float*)d_in[21];
    const float* b_v           = (const float*)d_in[22];
    const float* W_na_user     = (const float*)d_in[23];
    const float* W_na_item     = (const float*)d_in[24];
    const float* ln_gamma      = (const float*)d_in[25];
    const float* ln_beta       = (const float*)d_in[26];

    // fp8 buffers first (byte-addressed), then 16B-aligned bf16/f32 sections
    unsigned char* esf8 = (unsigned char*)d_ws;            // 25,600,000 B
    unsigned char* P8   = esf8 + 25600000;                 // 51,200,000 B
    unsigned short* v_b = (unsigned short*)(P8 + 51200000);// 51,200,000 u16 (16B-aligned)
    float* fz     = (float*)(v_b + 51200000);
    float* aq     = fz;                            // 800,000
    float* ak     = aq + 800000;                   // 1,600,000
    float* wq_eff = ak + 1600000;                  // 1024
    float* wk_eff = wq_eff + 1024;                 // 1024
    float* bq_eff = wk_eff + 1024;                 // 16
    float* bk_eff = bq_eff + 16;                   // 16
    float* Wcomb  = bk_eff + 16;                   // 1024
    float* cmv    = Wcomb + 1024;                  // 8
    int*   cnt       = (int*)(cmv + 8);            // N_DST
    int*   bsum      = cnt + N_DST;                // 128
    int*   boff      = bsum + 128;                 // 128
    int*   row_start = boff + 128;                 // N_DST + 1
    int*   cursor    = row_start + N_DST + 1;      // N_DST
    int*   eorder    = cursor + N_DST;             // NE
    unsigned short* wub = (unsigned short*)(((uintptr_t)(eorder + NE) + 15) & ~(uintptr_t)15);
    unsigned short* wib = wub + 128 * 320;
    unsigned short* web = wib + 128 * 224;
    unsigned short* wvb = web + 128 * 64;          // 256*128
    unsigned short* wqf = wvb + 256 * 128;         // 2048
    unsigned short* wkf = wqf + 2048;              // 2048
    size_t needed = (size_t)((char*)(wkf + 2048) - (char*)d_ws);
    if (ws_size < needed) {
        fprintf(stderr, "kernel_launch: ws_size %zu < needed %zu\n", ws_size, needed);
        return;
    }

    hipMemsetAsync(cnt, 0, N_DST * sizeof(int), stream);

    eff_setup<<<1, 256, 0, stream>>>(W_q, b_q, W_na_item, W_k, b_k, W_na_user,
                                     W_merge, b_merge, W_eattn, b_eattn,
                                     wq_eff, bq_eff, wk_eff, bk_eff, Wcomb, cmv,
                                     wqf, wkf);

    wconv_frag<<<64, 256, 0, stream>>>(W_nf_user, wub, 128, 300, 320);
    wconv_frag<<<64, 256, 0, stream>>>(W_nf_item, wib, 128, 200, 224);
    wconv_frag<<<32, 256, 0, stream>>>(W_ef,      web, 128,  64,  64);
    wconv_frag<<<64, 256, 0, stream>>>(W_v,       wvb, 256, 128, 128);

    // GEMM1 fused: src_feat -> esf8 (fp8 exp), v_b (FUSEV), ak (DOT)
    gemm_fused<300, 320, 8, true, true><<<dim3(1, 1563), 256, 0, stream>>>(
        x_user, wub, b_nf_user, node_emb_user, edge_emb,
        nullptr, esf8, wvb, b_v, v_b, wkf, ak, N_SRC, 128);
    // GEMM2 fused: dst_feat -> aq only
    gemm_fused<200, 224, 8, false, true><<<dim3(1, 782), 256, 0, stream>>>(
        x_item, wib, b_nf_item, nullptr, edge_emb,
        nullptr, nullptr, nullptr, nullptr, nullptr, wqf, aq, N_DST, 128);
    // GEMM3: P = exp(edge_feats@W_ef^T + b_ef) -> P8 (fp8)
    gemm_fused<64, 64, 8, false, false><<<dim3(1, 3125), 256, 0, stream>>>(
        edge_feats, web, b_ef, nullptr, nullptr,
        nullptr, P8, nullptr, nullptr, nullptr, nullptr, nullptr, NE, 128);

    // CSR build
    hist_kernel<<<1563, 256, 0, stream>>>(dst_idx, cnt);
    blocksum_kernel<<<NSCAN, 256, 0, stream>>>(cnt, bsum);
    scanoff_kernel<<<1, 64, 0, stream>>>(bsum, boff);
    rowstart_kernel<<<NSCAN, 256, 0, stream>>>(cnt, boff, row_start, cursor);
    scatter_kernel<<<1563, 256, 0, stream>>>(dst_idx, cursor, eorder);

    // mega-fused gather + LN
    fused_gather4<<<25000, 256, 0, stream>>>(
        row_start, eorder, src_idx, P8, esf8, v_b, aq, ak,
        Wcomb, cmv, W_merge, ln_gamma, ln_beta, (float*)d_out);
}

// Round 13
// 588.286 us; speedup vs baseline: 1.6151x; 1.1088x over previous
//
#include <hip/hip_runtime.h>
#include <hip/hip_fp16.h>
#include <math.h>
#include <stdio.h>
#include <stdint.h>

#define N_SRC 200000
#define N_DST 100000
#define NE    400000
// IN=128, H=8, D=32, H*D=256

#define SCAN_CHUNK 1024
#define NSCAN ((N_DST + SCAN_CHUNK - 1) / SCAN_CHUNK)   // 98

typedef short bf16x8 __attribute__((ext_vector_type(8)));
typedef float f32x4 __attribute__((ext_vector_type(4)));

__device__ __forceinline__ float bflo(unsigned int u) { return __uint_as_float(u << 16); }
__device__ __forceinline__ float bfhi(unsigned int u) { return __uint_as_float(u & 0xFFFF0000u); }
__device__ __forceinline__ unsigned short f2bf(float f) {
    unsigned int u = __float_as_uint(f);
    u += 0x7FFFu + ((u >> 16) & 1u);       // round-to-nearest-even
    return (unsigned short)(u >> 16);
}
__device__ __forceinline__ unsigned int packbf(float f0, float f1) {
    return __builtin_amdgcn_perm(__float_as_uint(f1), __float_as_uint(f0), 0x07060302u);
}
// f32 -> fp8 e5m2 (via f16 RNE, then RNE to top 8 bits)
__device__ __forceinline__ unsigned char f2e5(float f) {
    __half h = __float2half(f);
    unsigned short b = *reinterpret_cast<unsigned short*>(&h);
    b = (unsigned short)(b + 0x7Fu + ((b >> 8) & 1u));
    return (unsigned char)(b >> 8);
}
// fp8 e5m2 -> f32
__device__ __forceinline__ float e52f(unsigned int b8) {
    unsigned short h = (unsigned short)(b8 << 8);
    __half hh = *reinterpret_cast<__half*>(&h);
    return __half2float(hh);
}
// async global->LDS DMA, 16 bytes per lane
__device__ __forceinline__ void gl2lds(const void* g, void* l) {
    __builtin_amdgcn_global_load_lds(
        (const __attribute__((address_space(1))) unsigned int*)g,
        (__attribute__((address_space(3))) unsigned int*)l, 16, 0, 0);
}

// ---------------------------------------------------------------------------
// Generic fused GEMM body (device function, one tile of 128 rows x 128 cols).
// A via gl_lds double-buffer (source-swizzled chunks); B-fragments loaded to
// REGISTERS per step from L2 (issued BEFORE the A-stage so compiler pb-waits
// leave the prefetched A in flight: entry 4 oldA -> +8 B -> +4 newA;
// vmcnt(12) drains exactly oldA; pb uses drain to vmcnt(4)).
// Epilogue writes bf16 (out_lin) / fp8-e5m2 exp (out_exp); optional T-tile in
// LDS feeding FUSEV (v = sf@Wv^T + b_v) and DOT (8-head row dots).
// ---------------------------------------------------------------------------
template<int K, int KP, int NT, bool FUSEV, bool DOT>
__device__ __forceinline__ void gemm_body(
    int tileY, char* LDSB,
    const float* __restrict__ Ap, const unsigned short* __restrict__ Wf,
    const float* __restrict__ bias, const float* __restrict__ add_n,
    const float* __restrict__ add_c,
    unsigned short* __restrict__ out_lin, unsigned char* __restrict__ out_exp,
    const unsigned short* __restrict__ wvfrag, const float* __restrict__ bv,
    unsigned short* __restrict__ vout,
    const unsigned short* __restrict__ dotfrag, float* __restrict__ dotout,
    int N, int C)
{
    constexpr int KST = KP / 32;
    char* As = LDSB;            // 2 x 16384 (f32 A step)
    char* T  = LDSB;            // 128 x 256B bf16 sf tile (reused after main)

    const int tid  = threadIdx.x;
    const int lane = tid & 63;
    const int wv   = tid >> 6;
    const int fr   = lane & 15;
    const int fq   = lane >> 4;
    const int row0 = tileY * 128;
    const int NTC  = C / 16;

    f32x4 acc[2][NT];
#pragma unroll
    for (int m = 0; m < 2; ++m)
#pragma unroll
        for (int n = 0; n < NT; ++n) acc[m][n] = (f32x4){0.f, 0.f, 0.f, 0.f};

    const int csw = (lane & 7) ^ (lane >> 3);   // source-swizzled chunk (A stage)

    auto stageA = [&](int buf, int ks) {
        char* ab = As + buf * 16384;
        const char* Af = (const char*)Ap;
#pragma unroll
        for (int q = 0; q < 4; ++q) {
            int i   = wv * 4 + q;
            int row = i * 8 + (lane >> 3);
            int rr  = row0 + row; if (rr >= N) rr = N - 1;
            int kk  = ks * 32 + csw * 4;
            long off = (long)rr * K + ((kk + 4 <= K) ? kk : 0);
            gl2lds(Af + off * 4, ab + i * 1024 + lane * 16);
        }
    };

    stageA(0, 0);
    for (int ks = 0; ks < KST; ++ks) {
        const int cur = ks & 1;
        // B fragments -> registers (issued FIRST so pb-waits don't drain newA)
        uint4 pb[NT];
#pragma unroll
        for (int n = 0; n < NT; ++n)
            pb[n] = *(const uint4*)&Wf[(((size_t)ks * NTC + n) * 64 + lane) * 8];
        if (ks + 1 < KST) {
            stageA(cur ^ 1, ks + 1);
            asm volatile("s_waitcnt vmcnt(12)" ::: "memory");
        } else {
            asm volatile("s_waitcnt vmcnt(8)" ::: "memory");
        }
        __builtin_amdgcn_s_barrier();

        const char* ab = As + cur * 16384;
        const int rA = fr & 7;
        float4 f0 = *(const float4*)(ab + (wv * 32 +      fr) * 128 + ((2 * fq)     ^ rA) * 16);
        float4 f1 = *(const float4*)(ab + (wv * 32 +      fr) * 128 + ((2 * fq + 1) ^ rA) * 16);
        float4 f2 = *(const float4*)(ab + (wv * 32 + 16 + fr) * 128 + ((2 * fq)     ^ rA) * 16);
        float4 f3 = *(const float4*)(ab + (wv * 32 + 16 + fr) * 128 + ((2 * fq + 1) ^ rA) * 16);
        uint4 u0, u1;
        u0.x = packbf(f0.x, f0.y); u0.y = packbf(f0.z, f0.w);
        u0.z = packbf(f1.x, f1.y); u0.w = packbf(f1.z, f1.w);
        u1.x = packbf(f2.x, f2.y); u1.y = packbf(f2.z, f2.w);
        u1.z = packbf(f3.x, f3.y); u1.w = packbf(f3.z, f3.w);
        bf16x8 a0 = *(bf16x8*)&u0;
        bf16x8 a1 = *(bf16x8*)&u1;
#pragma unroll
        for (int n = 0; n < NT; ++n) {
            acc[0][n] = __builtin_amdgcn_mfma_f32_16x16x32_bf16(a0, *(bf16x8*)&pb[n], acc[0][n], 0, 0, 0);
            acc[1][n] = __builtin_amdgcn_mfma_f32_16x16x32_bf16(a1, *(bf16x8*)&pb[n], acc[1][n], 0, 0, 0);
        }
        asm volatile("s_waitcnt lgkmcnt(0)" ::: "memory");
        __builtin_amdgcn_s_barrier();
    }

    // ---- main epilogue: D col = lane&15, row = (lane>>4)*4 + reg (m89/m91) ----
    float bc[NT];
#pragma unroll
    for (int n = 0; n < NT; ++n) {
        int col = n * 16 + fr;
        float b = 0.f;
        if (bias)  b += bias[col];
        if (add_c) b += add_c[col];
        bc[n] = b;
    }
#pragma unroll
    for (int m = 0; m < 2; ++m) {
#pragma unroll
        for (int j = 0; j < 4; ++j) {
            int rl  = wv * 32 + m * 16 + fq * 4 + j;   // local row
            int row = row0 + rl;
            bool rok = (row < N);
#pragma unroll
            for (int n = 0; n < NT; ++n) {
                int col = n * 16 + fr;
                float v = acc[m][n][j] + bc[n];
                if (add_n && rok) v += add_n[(long)row * C + col];
                unsigned short bf = f2bf(v);
                if (FUSEV || DOT) {
                    int c = col >> 3;
                    *(unsigned short*)(T + rl * 256 + ((c ^ (rl & 7)) * 16) + (col & 7) * 2) = bf;
                }
                if (rok) {
                    long o = (long)row * C + col;
                    if (out_lin) out_lin[o] = bf;
                    if (out_exp) out_exp[o] = f2e5(expf(v));
                }
            }
        }
    }

    if (FUSEV || DOT) {
        __syncthreads();    // T fully written
        auto tfrag = [&](int r, int c) -> bf16x8 {
            return *(const bf16x8*)(T + r * 256 + ((c ^ (r & 7)) * 16));
        };
        if (DOT) {
            f32x4 da[2];
            da[0] = (f32x4){0.f, 0.f, 0.f, 0.f};
            da[1] = (f32x4){0.f, 0.f, 0.f, 0.f};
#pragma unroll
            for (int ks = 0; ks < 4; ++ks) {
                bf16x8 bf = *(const bf16x8*)&dotfrag[((size_t)ks * 64 + lane) * 8];
                bf16x8 t0 = tfrag(wv * 32 +      fr, ks * 4 + fq);
                bf16x8 t1 = tfrag(wv * 32 + 16 + fr, ks * 4 + fq);
                da[0] = __builtin_amdgcn_mfma_f32_16x16x32_bf16(t0, bf, da[0], 0, 0, 0);
                da[1] = __builtin_amdgcn_mfma_f32_16x16x32_bf16(t1, bf, da[1], 0, 0, 0);
            }
#pragma unroll
            for (int m = 0; m < 2; ++m)
#pragma unroll
                for (int j = 0; j < 4; ++j) {
                    int row = row0 + wv * 32 + m * 16 + fq * 4 + j;
                    if (fr < 8 && row < N) dotout[(long)row * 8 + fr] = da[m][j];
                }
        }
        if (FUSEV) {
#pragma unroll
            for (int half = 0; half < 2; ++half) {
                f32x4 va[2][8];
#pragma unroll
                for (int m = 0; m < 2; ++m)
#pragma unroll
                    for (int n = 0; n < 8; ++n) va[m][n] = (f32x4){0.f, 0.f, 0.f, 0.f};
#pragma unroll
                for (int ks = 0; ks < 4; ++ks) {
                    bf16x8 t0 = tfrag(wv * 32 +      fr, ks * 4 + fq);
                    bf16x8 t1 = tfrag(wv * 32 + 16 + fr, ks * 4 + fq);
                    uint4 vb4[8];
#pragma unroll
                    for (int n = 0; n < 8; ++n)
                        vb4[n] = *(const uint4*)&wvfrag[(((size_t)ks * 16 + half * 8 + n) * 64 + lane) * 8];
#pragma unroll
                    for (int n = 0; n < 8; ++n) {
                        va[0][n] = __builtin_amdgcn_mfma_f32_16x16x32_bf16(t0, *(bf16x8*)&vb4[n], va[0][n], 0, 0, 0);
                        va[1][n] = __builtin_amdgcn_mfma_f32_16x16x32_bf16(t1, *(bf16x8*)&vb4[n], va[1][n], 0, 0, 0);
                    }
                }
#pragma unroll
                for (int m = 0; m < 2; ++m)
#pragma unroll
                    for (int j = 0; j < 4; ++j) {
                        int row = row0 + wv * 32 + m * 16 + fq * 4 + j;
                        if (row >= N) continue;
#pragma unroll
                        for (int n = 0; n < 8; ++n) {
                            int col = half * 128 + n * 16 + fr;
                            vout[(long)row * 256 + col] = f2bf(va[m][n][j] + bv[col]);
                        }
                    }
            }
        }
    }
}

// ---------------------------------------------------------------------------
// Merged triple-GEMM dispatch: block-type interleaved via blockIdx.x % 7
// (2/7 -> GEMM1, 1/7 -> GEMM2, 4/7 -> GEMM3) so each CU co-hosts a MIX of
// independent blocks whose memory stalls overlap. 32KB LDS -> 5 blocks/CU.
// ---------------------------------------------------------------------------
__global__ __launch_bounds__(256) void gemm_all(
    const float* __restrict__ x_user, const unsigned short* __restrict__ wub,
    const float* __restrict__ b_nf_user, const float* __restrict__ node_emb_user,
    const float* __restrict__ edge_emb,
    unsigned char* __restrict__ esf8,
    const unsigned short* __restrict__ wvb, const float* __restrict__ bv,
    unsigned short* __restrict__ v_b,
    const unsigned short* __restrict__ wkf, float* __restrict__ ak,
    const float* __restrict__ x_item, const unsigned short* __restrict__ wib,
    const float* __restrict__ b_nf_item,
    const unsigned short* __restrict__ wqf, float* __restrict__ aq,
    const float* __restrict__ edge_feats, const unsigned short* __restrict__ web,
    const float* __restrict__ b_ef, unsigned char* __restrict__ P8)
{
    __shared__ __align__(16) char LDSB[32768];
    int gid = blockIdx.x;
    int b = gid / 7;
    int r = gid - b * 7;
    if (r < 2) {
        int t = b * 2 + r;
        if (t < 1563)
            gemm_body<300, 320, 8, true, true>(t, LDSB,
                x_user, wub, b_nf_user, node_emb_user, edge_emb,
                nullptr, esf8, wvb, bv, v_b, wkf, ak, N_SRC, 128);
    } else if (r == 2) {
        gemm_body<200, 224, 8, false, true>(b, LDSB,
            x_item, wib, b_nf_item, nullptr, edge_emb,
            nullptr, nullptr, nullptr, nullptr, nullptr, wqf, aq, N_DST, 128);
    } else {
        int t = b * 4 + (r - 3);
        if (t < 3125)
            gemm_body<64, 64, 8, false, false>(t, LDSB,
                edge_feats, web, b_ef, nullptr, nullptr,
                nullptr, P8, nullptr, nullptr, nullptr, nullptr, nullptr, NE, 128);
    }
}

// ---------------------------------------------------------------------------
// Weight f32 [C][K] -> bf16 B-fragment layout, [ks][n] major (padded K).
// ---------------------------------------------------------------------------
__global__ void wconv_frag(const float* __restrict__ src, unsigned short* __restrict__ dst,
                           int C, int K, int Kp)
{
    int NTC = C >> 4;
    int total = C * Kp;
    for (int i = blockIdx.x * blockDim.x + threadIdx.x; i < total; i += gridDim.x * blockDim.x) {
        int j  = i & 7;
        int l  = (i >> 3) & 63;
        int t  = i >> 9;
        int n  = t % NTC;
        int ks = t / NTC;
        int col = n * 16 + (l & 15);
        int k   = ks * 32 + ((l >> 4) << 3) + j;
        dst[i] = (k < K) ? f2bf(src[(long)col * K + k]) : (unsigned short)0;
    }
}

// ---------------------------------------------------------------------------
// Setup: folded weights + wq/wk zero-padded 16-col bf16 B-fragments.
// ---------------------------------------------------------------------------
__global__ void eff_setup(const float* __restrict__ Wq, const float* __restrict__ bq,
                          const float* __restrict__ na_item,
                          const float* __restrict__ Wk, const float* __restrict__ bk,
                          const float* __restrict__ na_user,
                          const float* __restrict__ W_merge, const float* __restrict__ b_merge,
                          const float* __restrict__ W_eattn, const float* __restrict__ b_eattn,
                          float* __restrict__ wq_eff, float* __restrict__ bq_eff,
                          float* __restrict__ wk_eff, float* __restrict__ bk_eff,
                          float* __restrict__ Wcomb, float* __restrict__ cmv,
                          unsigned short* __restrict__ wqf, unsigned short* __restrict__ wkf)
{
    int tid = threadIdx.x;
    for (int idx = tid; idx < 1024; idx += 256) {
        int h = idx >> 7, k = idx & 127;
        float s1 = 0.f, s2 = 0.f, s3 = 0.f;
        for (int d = 0; d < 32; ++d) {
            s1 += Wq[(h * 32 + d) * 128 + k] * na_item[d];
            s2 += Wk[(h * 32 + d) * 128 + k] * na_user[d];
        }
        for (int j = 0; j < 8; ++j)
            s3 += W_merge[h * 16 + 8 + j] * W_eattn[j * 128 + k];
        wq_eff[idx] = s1;
        wk_eff[idx] = s2;
        Wcomb[idx]  = s3;
    }
    if (tid < 8) {
        float s1 = 0.f, s2 = 0.f, s3 = b_merge[tid];
        for (int d = 0; d < 32; ++d) {
            s1 += bq[tid * 32 + d] * na_item[d];
            s2 += bk[tid * 32 + d] * na_user[d];
        }
        for (int j = 0; j < 8; ++j) s3 += W_merge[tid * 16 + 8 + j] * b_eattn[j];
        bq_eff[tid] = s1;
        bk_eff[tid] = s2;
        cmv[tid]    = s3;
    }
    __syncthreads();
    for (int idx = tid; idx < 2048; idx += 256) {
        int j  = idx & 7;
        int l  = (idx >> 3) & 63;
        int ks = idx >> 9;
        int col = l & 15;
        int k   = ks * 32 + ((l >> 4) << 3) + j;
        wqf[idx] = (col < 8) ? f2bf(wq_eff[col * 128 + k]) : (unsigned short)0;
        wkf[idx] = (col < 8) ? f2bf(wk_eff[col * 128 + k]) : (unsigned short)0;
    }
}

// ---------------------------------------------------------------------------
// CSR build: histogram -> two-level scan -> scatter
// ---------------------------------------------------------------------------
__global__ void hist_kernel(const int* __restrict__ dst_idx, int* __restrict__ cnt)
{
    int e = blockIdx.x * blockDim.x + threadIdx.x;
    if (e < NE) atomicAdd(&cnt[dst_idx[e]], 1);
}

__global__ __launch_bounds__(256) void blocksum_kernel(const int* __restrict__ cnt,
                                                       int* __restrict__ bsum)
{
    __shared__ int sm[256];
    int b = blockIdx.x, t = threadIdx.x;
    int s = 0;
    for (int i = t; i < SCAN_CHUNK; i += 256) {
        int idx = b * SCAN_CHUNK + i;
        if (idx < N_DST) s += cnt[idx];
    }
    sm[t] = s; __syncthreads();
    for (int off = 128; off > 0; off >>= 1) {
        if (t < off) sm[t] += sm[t + off];
        __syncthreads();
    }
    if (t == 0) bsum[b] = sm[0];
}

__global__ void scanoff_kernel(const int* __restrict__ bsum, int* __restrict__ boff)
{
    if (threadIdx.x == 0) {
        int r = 0;
        for (int i = 0; i < NSCAN; ++i) { boff[i] = r; r += bsum[i]; }
    }
}

__global__ __launch_bounds__(256) void rowstart_kernel(
    const int* __restrict__ cnt, const int* __restrict__ boff,
    int* __restrict__ row_start, int* __restrict__ cursor)
{
    __shared__ int sm[256];
    int b = blockIdx.x, t = threadIdx.x;
    int base = b * SCAN_CHUNK + t * 4;
    int c[4]; int tot = 0;
#pragma unroll
    for (int j = 0; j < 4; ++j) {
        int idx = base + j;
        c[j] = (idx < N_DST) ? cnt[idx] : 0;
        tot += c[j];
    }
    sm[t] = tot; __syncthreads();
    for (int off = 1; off < 256; off <<= 1) {
        int v = (t >= off) ? sm[t - off] : 0;
        __syncthreads();
        sm[t] += v;
        __syncthreads();
    }
    int run = sm[t] - tot + boff[b];
#pragma unroll
    for (int j = 0; j < 4; ++j) {
        int idx = base + j;
        if (idx < N_DST) { row_start[idx] = run; cursor[idx] = run; run += c[j]; }
    }
    if (b == 0 && t == 0) row_start[N_DST] = NE;
}

__global__ void scatter_kernel(const int* __restrict__ dst_idx,
                               int* __restrict__ cursor, int* __restrict__ eorder)
{
    int e = blockIdx.x * blockDim.x + threadIdx.x;
    if (e >= NE) return;
    int pos = atomicAdd(&cursor[dst_idx[e]], 1);
    eorder[pos] = e;
}

// ---------------------------------------------------------------------------
// Mega-fused gather v4: batch-issued register cache + fp8 P/esf decode.
// ---------------------------------------------------------------------------
__global__ __launch_bounds__(256) void fused_gather4(
    const int* __restrict__ row_start, const int* __restrict__ eorder,
    const int* __restrict__ src_idx,
    const unsigned char* __restrict__ Pb, const unsigned char* __restrict__ esfb,
    const unsigned short* __restrict__ vb,
    const float* __restrict__ aq, const float* __restrict__ ak,
    const float* __restrict__ Wcomb, const float* __restrict__ cmv,
    const float* __restrict__ W_merge,
    const float* __restrict__ ln_gamma, const float* __restrict__ ln_beta,
    float* __restrict__ out)
{
    int gw   = (blockIdx.x * blockDim.x + threadIdx.x) >> 6;
    int lane = threadIdx.x & 63;
    if (gw >= N_DST) return;
    const int dst = gw;
    const int r0 = row_start[dst], r1 = row_start[dst + 1];
    const int deg = r1 - r0;
    const int ch = lane * 2;
    const int hl = lane & 7;
    const int g  = lane >> 3;
    const float rsc = 0.17677669529663687f;   // 1/sqrt(32)

    float ax = 0.f, ay = 0.f, az = 0.f, aw = 0.f;

    if (deg > 0) {
        float wc0[8], wc1[8];
#pragma unroll
        for (int h = 0; h < 8; ++h) {
            wc0[h] = Wcomb[h * 128 + ch];
            wc1[h] = Wcomb[h * 128 + ch + 1];
        }
        const float wself = W_merge[g * 16 + hl];
        const float cmg   = cmv[g];
        const float aqh   = aq[(long)dst * 8 + hl];

        if (deg <= 8) {
            int eo[8], sr[8];
            unsigned int pu[8], su[8];
            float akv[8];
            uint2 vv[8];
#pragma unroll
            for (int j = 0; j < 8; ++j) { pu[j] = 0u; su[j] = 0u; akv[j] = 0.f;
                                          vv[j] = make_uint2(0u, 0u); }
#pragma unroll
            for (int j = 0; j < 8; ++j) if (j < deg) eo[j] = eorder[r0 + j];
#pragma unroll
            for (int j = 0; j < 8; ++j) if (j < deg) sr[j] = src_idx[eo[j]];
#pragma unroll
            for (int j = 0; j < 8; ++j) if (j < deg) {
                pu[j]  = *(const unsigned short*)&Pb[(long)eo[j] * 128 + ch];
                su[j]  = *(const unsigned short*)&esfb[(long)sr[j] * 128 + ch];
                akv[j] = ak[(long)sr[j] * 8 + hl];
                vv[j]  = *(const uint2*)&vb[(long)sr[j] * 256 + lane * 4];
            }
            float z0[8], z1[8], ex[8];
            float s1x = 0.f, s1y = 0.f, s2l = 0.f;
#pragma unroll
            for (int j = 0; j < 8; ++j) {
                z0[j] = e52f(pu[j] & 0xFFu) * e52f(su[j] & 0xFFu);
                z1[j] = e52f(pu[j] >> 8)    * e52f(su[j] >> 8);
                s1x += z0[j];
                s1y += z1[j];
                float e = expf((akv[j] + aqh) * rsc);
                ex[j] = (j < deg) ? e : 0.f;
                s2l += ex[j];
            }
            const float i1x = 1.0f / fmaxf(s1x, 1e-35f);
            const float i1y = 1.0f / fmaxf(s1y, 1e-35f);
            const float i2  = 1.0f / s2l;
#pragma unroll
            for (int j = 0; j < 8; ++j) if (j < deg) {
                float t0 = z0[j] * i1x;
                float t1 = z1[j] * i1y;
                float part[8];
#pragma unroll
                for (int h = 0; h < 8; ++h) part[h] = t0 * wc0[h] + t1 * wc1[h];
                int b0 = lane & 1, b1 = (lane >> 1) & 1, b2 = (lane >> 2) & 1;
                float u0 = (b0 ? part[1] : part[0]) + __shfl_xor(b0 ? part[0] : part[1], 1);
                float u1 = (b0 ? part[3] : part[2]) + __shfl_xor(b0 ? part[2] : part[3], 1);
                float u2 = (b0 ? part[5] : part[4]) + __shfl_xor(b0 ? part[4] : part[5], 1);
                float u3 = (b0 ? part[7] : part[6]) + __shfl_xor(b0 ? part[6] : part[7], 1);
                float w0 = (b1 ? u1 : u0) + __shfl_xor(b1 ? u0 : u1, 2);
                float w1 = (b1 ? u3 : u2) + __shfl_xor(b1 ? u2 : u3, 2);
                float ts = (b2 ? w1 : w0) + __shfl_xor(b2 ? w0 : w1, 4);
                ts += __shfl_xor(ts, 8);
                ts += __shfl_xor(ts, 16);
                ts += __shfl_xor(ts, 32);
                float ms = wself * (ex[j] * i2);
                ms += __shfl_xor(ms, 1);
                ms += __shfl_xor(ms, 2);
                ms += __shfl_xor(ms, 4);
                float mm = cmg + ms + __shfl(ts, g);
                ax += mm * bflo(vv[j].x); ay += mm * bfhi(vv[j].x);
                az += mm * bflo(vv[j].y); aw += mm * bfhi(vv[j].y);
            }
        } else {
            float s1x = 0.f, s1y = 0.f, s2l = 0.f;
            for (int j = r0; j < r1; ++j) {
                int eo  = eorder[j];
                int src = src_idx[eo];
                unsigned int pu = *(const unsigned short*)&Pb[(long)eo * 128 + ch];
                unsigned int su = *(const unsigned short*)&esfb[(long)src * 128 + ch];
                float akh = ak[(long)src * 8 + hl];
                s1x += e52f(pu & 0xFFu) * e52f(su & 0xFFu);
                s1y += e52f(pu >> 8)    * e52f(su >> 8);
                s2l += expf((akh + aqh) * rsc);
            }
            const float i1x = 1.0f / fmaxf(s1x, 1e-35f);
            const float i1y = 1.0f / fmaxf(s1y, 1e-35f);
            const float i2  = 1.0f / s2l;
            for (int j = r0; j < r1; ++j) {
                int eo  = eorder[j];
                int src = src_idx[eo];
                unsigned int pu = *(const unsigned short*)&Pb[(long)eo * 128 + ch];
                unsigned int su = *(const unsigned short*)&esfb[(long)src * 128 + ch];
                float akh = ak[(long)src * 8 + hl];
                uint2 vv = *(const uint2*)&vb[(long)src * 256 + lane * 4];
                float t0 = e52f(pu & 0xFFu) * e52f(su & 0xFFu) * i1x;
                float t1 = e52f(pu >> 8)    * e52f(su >> 8)    * i1y;
                float part[8];
#pragma unroll
                for (int h = 0; h < 8; ++h) part[h] = t0 * wc0[h] + t1 * wc1[h];
                int b0 = lane & 1, b1 = (lane >> 1) & 1, b2 = (lane >> 2) & 1;
                float u0 = (b0 ? part[1] : part[0]) + __shfl_xor(b0 ? part[0] : part[1], 1);
                float u1 = (b0 ? part[3] : part[2]) + __shfl_xor(b0 ? part[2] : part[3], 1);
                float u2 = (b0 ? part[5] : part[4]) + __shfl_xor(b0 ? part[4] : part[5], 1);
                float u3 = (b0 ? part[7] : part[6]) + __shfl_xor(b0 ? part[6] : part[7], 1);
                float w0 = (b1 ? u1 : u0) + __shfl_xor(b1 ? u0 : u1, 2);
                float w1 = (b1 ? u3 : u2) + __shfl_xor(b1 ? u2 : u3, 2);
                float ts = (b2 ? w1 : w0) + __shfl_xor(b2 ? w0 : w1, 4);
                ts += __shfl_xor(ts, 8);
                ts += __shfl_xor(ts, 16);
                ts += __shfl_xor(ts, 32);
                float ms = wself * (expf((akh + aqh) * rsc) * i2);
                ms += __shfl_xor(ms, 1);
                ms += __shfl_xor(ms, 2);
                ms += __shfl_xor(ms, 4);
                float mm = cmg + ms + __shfl(ts, g);
                ax += mm * bflo(vv.x); ay += mm * bfhi(vv.x);
                az += mm * bflo(vv.y); aw += mm * bfhi(vv.y);
            }
        }
    }

    float s = ax + ay + az + aw;
    float q = ax * ax + ay * ay + az * az + aw * aw;
#pragma unroll
    for (int off = 32; off > 0; off >>= 1) {
        s += __shfl_xor(s, off);
        q += __shfl_xor(q, off);
    }
    float mu  = s * (1.0f / 256.0f);
    float var = q * (1.0f / 256.0f) - mu * mu;
    float inv = rsqrtf(var + 1e-5f);
    float4 gg = *(const float4*)&ln_gamma[lane * 4];
    float4 bb = *(const float4*)&ln_beta[lane * 4];
    float4 o;
    o.x = (ax - mu) * inv * gg.x + bb.x;
    o.y = (ay - mu) * inv * gg.y + bb.y;
    o.z = (az - mu) * inv * gg.z + bb.z;
    o.w = (aw - mu) * inv * gg.w + bb.w;
    *(float4*)&out[(long)dst * 256 + lane * 4] = o;
}

// ---------------------------------------------------------------------------
extern "C" void kernel_launch(void* const* d_in, const int* in_sizes, int n_in,
                              void* d_out, int out_size, void* d_ws, size_t ws_size,
                              hipStream_t stream)
{
    const float* x_user        = (const float*)d_in[0];
    const float* x_item        = (const float*)d_in[1];
    const float* node_emb_user = (const float*)d_in[2];
    const float* edge_emb      = (const float*)d_in[3];
    const float* edge_feats    = (const float*)d_in[4];
    const int*   src_idx       = (const int*)d_in[5];
    const int*   dst_idx       = (const int*)d_in[6];
    const float* W_nf_user     = (const float*)d_in[7];
    const float* b_nf_user     = (const float*)d_in[8];
    const float* W_nf_item     = (const float*)d_in[9];
    const float* b_nf_item     = (const float*)d_in[10];
    const float* W_ef          = (const float*)d_in[11];
    const float* b_ef          = (const float*)d_in[12];
    const float* W_eattn       = (const float*)d_in[13];
    const float* b_eattn       = (const float*)d_in[14];
    const float* W_merge       = (const float*)d_in[15];
    const float* b_merge       = (const float*)d_in[16];
    const float* W_q           = (const float*)d_in[17];
    const float* b_q           = (const float*)d_in[18];
    const float* W_k           = (const float*)d_in[19];
    const float* b_k           = (const float*)d_in[20];
    const float* W_v           = (const float*)d_in[21];
    const float* b_v           = (const float*)d_in[22];
    const float* W_na_user     = (const float*)d_in[23];
    const float* W_na_item     = (const float*)d_in[24];
    const float* ln_gamma      = (const float*)d_in[25];
    const float* ln_beta       = (const float*)d_in[26];

    // fp8 buffers first (byte-addressed), then 16B-aligned bf16/f32 sections
    unsigned char* esf8 = (unsigned char*)d_ws;            // 25,600,000 B
    unsigned char* P8   = esf8 + 25600000;                 // 51,200,000 B
    unsigned short* v_b = (unsigned short*)(P8 + 51200000);// 51,200,000 u16 (16B-aligned)
    float* fz     = (float*)(v_b + 51200000);
    float* aq     = fz;                            // 800,000
    float* ak     = aq + 800000;                   // 1,600,000
    float* wq_eff = ak + 1600000;                  // 1024
    float* wk_eff = wq_eff + 1024;                 // 1024
    float* bq_eff = wk_eff + 1024;                 // 16
    float* bk_eff = bq_eff + 16;                   // 16
    float* Wcomb  = bk_eff + 16;                   // 1024
    float* cmv    = Wcomb + 1024;                  // 8
    int*   cnt       = (int*)(cmv + 8);            // N_DST
    int*   bsum      = cnt + N_DST;                // 128
    int*   boff      = bsum + 128;                 // 128
    int*   row_start = boff + 128;                 // N_DST + 1
    int*   cursor    = row_start + N_DST + 1;      // N_DST
    int*   eorder    = cursor + N_DST;             // NE
    unsigned short* wub = (unsigned short*)(((uintptr_t)(eorder + NE) + 15) & ~(uintptr_t)15);
    unsigned short* wib = wub + 128 * 320;
    unsigned short* web = wib + 128 * 224;
    unsigned short* wvb = web + 128 * 64;          // 256*128
    unsigned short* wqf = wvb + 256 * 128;         // 2048
    unsigned short* wkf = wqf + 2048;              // 2048
    size_t needed = (size_t)((char*)(wkf + 2048) - (char*)d_ws);
    if (ws_size < needed) {
        fprintf(stderr, "kernel_launch: ws_size %zu < needed %zu\n", ws_size, needed);
        return;
    }

    hipMemsetAsync(cnt, 0, N_DST * sizeof(int), stream);

    eff_setup<<<1, 256, 0, stream>>>(W_q, b_q, W_na_item, W_k, b_k, W_na_user,
                                     W_merge, b_merge, W_eattn, b_eattn,
                                     wq_eff, bq_eff, wk_eff, bk_eff, Wcomb, cmv,
                                     wqf, wkf);

    wconv_frag<<<64, 256, 0, stream>>>(W_nf_user, wub, 128, 300, 320);
    wconv_frag<<<64, 256, 0, stream>>>(W_nf_item, wib, 128, 200, 224);
    wconv_frag<<<32, 256, 0, stream>>>(W_ef,      web, 128,  64,  64);
    wconv_frag<<<64, 256, 0, stream>>>(W_v,       wvb, 256, 128, 128);

    // merged triple-GEMM (interleaved block types; 7 buckets of 782)
    gemm_all<<<5474, 256, 0, stream>>>(
        x_user, wub, b_nf_user, node_emb_user, edge_emb,
        esf8, wvb, b_v, v_b, wkf, ak,
        x_item, wib, b_nf_item, wqf, aq,
        edge_feats, web, b_ef, P8);

    // CSR build
    hist_kernel<<<1563, 256, 0, stream>>>(dst_idx, cnt);
    blocksum_kernel<<<NSCAN, 256, 0, stream>>>(cnt, bsum);
    scanoff_kernel<<<1, 64, 0, stream>>>(bsum, boff);
    rowstart_kernel<<<NSCAN, 256, 0, stream>>>(cnt, boff, row_start, cursor);
    scatter_kernel<<<1563, 256, 0, stream>>>(dst_idx, cursor, eorder);

    // mega-fused gather + LN
    fused_gather4<<<25000, 256, 0, stream>>>(
        row_start, eorder, src_idx, P8, esf8, v_b, aq, ak,
        Wcomb, cmv, W_merge, ln_gamma, ln_beta, (float*)d_out);
}